// Round 2
// 2494.851 us; speedup vs baseline: 2.0317x; 2.0317x over previous
//
#include <hip/hip_runtime.h>
#include <math.h>

// ---------------- problem constants ----------------
#define T_IN  16
#define T1    14
#define T2    12
#define NB    16
#define NPROP 4096
#define NDEV  1024
#define NROOM 256
#define NR    4096    // B*N_ROOM
#define ND    16384   // B*N_DEV
#define NP    65536   // B*N_PROP
// B*N_OUT = B*N_TIME = 16

// ---------------- workspace layout (floats) ----------------
constexpr size_t SZ_PF = (size_t)T1 * NP * 64;   // 58,720,256
constexpr size_t SZ_DF = (size_t)T1 * ND * 64;   // 14,680,064
constexpr size_t SZ_RF = (size_t)T1 * NR * 64;   //  3,670,016
constexpr size_t SZ_OF = (size_t)T1 * 16 * 64;   //     14,336

constexpr size_t O_PF   = 0;
constexpr size_t O_DF   = O_PF + SZ_PF;
constexpr size_t O_RF   = O_DF + SZ_DF;
constexpr size_t O_H0   = O_RF + SZ_RF;
constexpr size_t O_H1   = O_H0 + SZ_RF;
constexpr size_t O_OF   = O_H1 + SZ_RF;
constexpr size_t O_TF   = O_OF + SZ_OF;
constexpr size_t O_WSR  = O_TF + SZ_OF;      // Wr0+Wr2+Wr3 (4096)
constexpr size_t O_WSD  = O_WSR + 4096;      // Wr1+Wr4     (4096)
constexpr size_t O_BSR  = O_WSD + 4096;      // summed room bias (64)
constexpr size_t O_BSD  = O_BSR + 64;        // summed dev bias  (64)
constexpr size_t O_DINV0= O_BSD + 64;
constexpr size_t O_DINV1= O_DINV0 + 4096;
constexpr size_t O_RCDR = O_DINV1 + 4096;
constexpr size_t O_RCOR = O_RCDR + 4096;
constexpr size_t O_RCTR = O_RCOR + 4096;
constexpr size_t O_RCPD = O_RCTR + 4096;
constexpr size_t O_RCTD = O_RCPD + 16384;
constexpr size_t O_RCTP = O_RCTD + 16384;
// bf16 conv weights, k-permuted (k' = kk*64 + i): [128][192] shorts each
constexpr size_t O_WB1  = O_RCTP + 65536;    // 24576 shorts = 12288 float slots
constexpr size_t O_WB2  = O_WB1 + 12288;
// split-bf16 transposed weight arrays for the final GEMMs (hi then lo)
constexpr size_t O_WFD  = O_WB2 + 12288;     // dev  [64][128] hi+lo = 16384 shorts = 8192 floats
constexpr size_t O_WFR  = O_WFD + 8192;      // room [64][128] hi+lo
constexpr size_t O_WFP  = O_WFR + 8192;      // prop [64][64]  hi+lo = 8192 shorts = 4096 floats
constexpr size_t O_WG   = O_WFP + 4096;      // gcn g0,g1 each [64][64] hi+lo = 8192 floats
// precomputed (tf/of @ Wl) products, fp32: [14][16][64] each
constexpr size_t O_OFW  = O_WG + 8192;       // of @ Wl2
constexpr size_t O_TRW  = O_OFW + 14336;     // tf @ Wl3
constexpr size_t O_TDW  = O_TRW + 14336;     // tf @ Wl4
constexpr size_t O_TPW  = O_TDW + 14336;     // tf @ Wl5
// ---- zero-initialized region starts here ----
constexpr size_t O_ZERO  = O_TPW + 14336;
constexpr size_t O_ROOMG = O_ZERO;                    // gcn edge scatter acc (3,670,016)
constexpr size_t O_AGGDR = O_ROOMG + SZ_RF;           // sage dr agg          (3,670,016)
constexpr size_t O_AGGPD = O_AGGDR + SZ_RF;           // sage pd agg         (14,680,064)
constexpr size_t O_DEG0  = O_AGGPD + SZ_DF;
constexpr size_t O_DEG1  = O_DEG0 + 4096;
constexpr size_t O_CNTDR = O_DEG1 + 4096;
constexpr size_t O_CNTPD = O_CNTDR + 4096;
constexpr size_t O_MOR   = O_CNTPD + 16384;           // 4096 x 16
constexpr size_t O_MTR   = O_MOR + 65536;             // 4096 x 16
constexpr size_t O_MTD   = O_MTR + 65536;             // 16384 x 16
constexpr size_t O_MTP   = O_MTD + 262144;            // 65536 x 16
constexpr size_t O_END   = O_MTP + 1048576;
constexpr size_t ZERO_CNT = O_END - O_ZERO;

// output (floats) offsets in d_out (NCHW, concatenated in return order)
constexpr size_t OUT_ROOM = 0;
constexpr size_t OUT_DEV  = 3145728;
constexpr size_t OUT_PROP = 15728640;
constexpr size_t OUT_OUT  = 66060288;
constexpr size_t OUT_TIME = 66072576;

__device__ __forceinline__ float sigm(float x) { return 1.f / (1.f + __expf(-x)); }

__device__ __forceinline__ unsigned short f2bf(float f) {
  unsigned u = __float_as_uint(f);
  u += 0x7fffu + ((u >> 16) & 1u);
  return (unsigned short)(u >> 16);
}
__device__ __forceinline__ float bf2f(unsigned short h) {
  return __uint_as_float(((unsigned)h) << 16);
}

typedef __attribute__((ext_vector_type(8))) short bf16x8;
typedef __attribute__((ext_vector_type(4))) float floatx4;

__device__ __forceinline__ floatx4 mfma16(bf16x8 a, bf16x8 b, floatx4 c) {
  return __builtin_amdgcn_mfma_f32_16x16x32_bf16(a, b, c, 0, 0, 0);
}

// split a float4 into bf16 hi + bf16 lo (x ~= hi + lo), store 8B each
__device__ __forceinline__ void split_store4(float4 v, unsigned short* ph, unsigned short* pl) {
  const unsigned short h0 = f2bf(v.x), h1 = f2bf(v.y), h2 = f2bf(v.z), h3 = f2bf(v.w);
  *(uint2*)ph = make_uint2((unsigned)h0 | ((unsigned)h1 << 16),
                           (unsigned)h2 | ((unsigned)h3 << 16));
  const unsigned short l0 = f2bf(v.x - bf2f(h0)), l1 = f2bf(v.y - bf2f(h1));
  const unsigned short l2 = f2bf(v.z - bf2f(h2)), l3 = f2bf(v.w - bf2f(h3));
  *(uint2*)pl = make_uint2((unsigned)l0 | ((unsigned)l1 << 16),
                           (unsigned)l2 | ((unsigned)l3 << 16));
}

// ---------------- small prep kernels ----------------
__global__ void k_prep(const float* __restrict__ sWr, const float* __restrict__ gcnb,
                       const float* __restrict__ sbl, float* __restrict__ Wsr,
                       float* __restrict__ Wsd, float* __restrict__ bsr, float* __restrict__ bsd) {
  const int k = blockIdx.x * 256 + threadIdx.x;
  if (k < 4096) {
    Wsr[k] = sWr[k] + sWr[2 * 4096 + k] + sWr[3 * 4096 + k];
    Wsd[k] = sWr[4096 + k] + sWr[4 * 4096 + k];
  }
  if (k < 64) {
    bsr[k] = gcnb[k] + gcnb[64 + k] + sbl[k] + sbl[2 * 64 + k] + sbl[3 * 64 + k];
    bsd[k] = sbl[64 + k] + sbl[4 * 64 + k];
  }
}

// convert prop conv weights (conv index 0) to bf16 with k' = kk*64 + i ordering
__global__ void k_wbf(const float* __restrict__ W1, const float* __restrict__ W2,
                      unsigned short* __restrict__ wb1, unsigned short* __restrict__ wb2) {
  const int idx = blockIdx.x * 256 + threadIdx.x;
  if (idx >= 128 * 192) return;
  const int o = idx / 192, kp = idx % 192;
  const int kk = kp >> 6, i = kp & 63;
  const size_t srcoff = (size_t)o * 192 + i * 3 + kk;
  wb1[idx] = f2bf(W1[srcoff]);
  wb2[idx] = f2bf(W2[srcoff]);
}

// build split-bf16 transposed weight arrays: A[o][k] layout for MFMA A-fragments
__global__ void k_wfin(const float* __restrict__ sWl, const float* __restrict__ sWr,
                       const float* __restrict__ gcnW, const float* __restrict__ Wsr,
                       const float* __restrict__ Wsd, unsigned short* __restrict__ wfd,
                       unsigned short* __restrict__ wfr, unsigned short* __restrict__ wfp,
                       unsigned short* __restrict__ wg) {
  const int idx = blockIdx.x * 256 + threadIdx.x;
  if (idx >= 28672) return;
  float w;
  unsigned short* hi;
  unsigned short* lo;
  if (idx < 8192) {  // dev: [Wl1 ; Wsd]
    const int o = idx >> 7, k = idx & 127;
    w = (k < 64) ? sWl[4096 + k * 64 + o] : Wsd[(k - 64) * 64 + o];
    hi = wfd + idx;
    lo = wfd + 8192 + idx;
  } else if (idx < 16384) {  // room: [Wl0 ; Wsr]
    const int j = idx - 8192;
    const int o = j >> 7, k = j & 127;
    w = (k < 64) ? sWl[k * 64 + o] : Wsr[(k - 64) * 64 + o];
    hi = wfr + j;
    lo = wfr + 8192 + j;
  } else if (idx < 20480) {  // prop: Wr5
    const int j = idx - 16384;
    const int o = j >> 6, k = j & 63;
    w = sWr[5 * 4096 + k * 64 + o];
    hi = wfp + j;
    lo = wfp + 4096 + j;
  } else {  // gcn W0, W1
    const int j = idx - 20480;
    const int g = j >> 12, jj = j & 4095;
    const int o = jj >> 6, k = jj & 63;
    w = gcnW[g * 4096 + k * 64 + o];
    hi = wg + g * 8192 + jj;
    lo = wg + g * 8192 + 4096 + jj;
  }
  const unsigned short h = f2bf(w);
  *hi = h;
  *lo = f2bf(w - bf2f(h));
}

// precompute (of|tf)[t][s] @ Wl{2,3,4,5} in fp32: outputs [l][14][16][64]
__global__ void k_wprod(const float* __restrict__ of, const float* __restrict__ tf,
                        const float* __restrict__ sWl, float* __restrict__ dstbase) {
  const int idx = blockIdx.x * 256 + threadIdx.x;  // 57344 total
  const int d = idx & 63, l = (idx >> 6) & 3, s = (idx >> 8) & 15, t = idx >> 12;
  if (t >= 14) return;
  const float* v = (l == 0 ? of : tf) + ((size_t)t * 16 + s) * 64;
  const float* W = sWl + (size_t)(l + 2) * 4096;
  float a = 0.f;
  for (int c = 0; c < 64; ++c) a += v[c] * W[c * 64 + d];
  dstbase[(size_t)l * 14336 + ((size_t)t * 16 + s) * 64 + d] = a;
}

__global__ void k_count_w(const int* __restrict__ dst, const float* __restrict__ w, int E,
                          float* __restrict__ deg) {
  const int e = blockIdx.x * 256 + threadIdx.x;
  if (e < E) atomicAdd(&deg[dst[e]], w[e]);
}
__global__ void k_count1(const int* __restrict__ dst, int E, float* __restrict__ cnt) {
  const int e = blockIdx.x * 256 + threadIdx.x;
  if (e < E) atomicAdd(&cnt[dst[e]], 1.f);
}
__global__ void k_cmat(const int* __restrict__ src, const int* __restrict__ dst, int E,
                       float* __restrict__ M) {
  const int e = blockIdx.x * 256 + threadIdx.x;
  if (e < E) atomicAdd(&M[(size_t)dst[e] * 16 + src[e]], 1.f);
}

__global__ void k_finalize(const float* __restrict__ deg0, const float* __restrict__ deg1,
                           const float* __restrict__ cntdr, const float* __restrict__ cntpd,
                           const float* __restrict__ MOR, const float* __restrict__ MTR,
                           const float* __restrict__ MTD, const float* __restrict__ MTP,
                           float* __restrict__ dinv0, float* __restrict__ dinv1,
                           float* __restrict__ rcdr, float* __restrict__ rcor,
                           float* __restrict__ rctr, float* __restrict__ rcpd,
                           float* __restrict__ rctd, float* __restrict__ rctp) {
  const int i = blockIdx.x * 256 + threadIdx.x;  // 65536 threads
  if (i < 4096) {
    dinv0[i] = rsqrtf(deg0[i] + 1.f);   // +1 = self-loop weight
    dinv1[i] = rsqrtf(deg1[i] + 1.f);
    rcdr[i] = 1.f / fmaxf(cntdr[i], 1.f);
    float s0 = 0.f, s1 = 0.f;
    for (int s = 0; s < 16; ++s) { s0 += MOR[i * 16 + s]; s1 += MTR[i * 16 + s]; }
    rcor[i] = 1.f / fmaxf(s0, 1.f);
    rctr[i] = 1.f / fmaxf(s1, 1.f);
  }
  if (i < 16384) {
    rcpd[i] = 1.f / fmaxf(cntpd[i], 1.f);
    float s = 0.f;
    for (int k = 0; k < 16; ++k) s += MTD[i * 16 + k];
    rctd[i] = 1.f / fmaxf(s, 1.f);
  }
  {
    float s = 0.f;
    for (int k = 0; k < 16; ++k) s += MTP[(size_t)i * 16 + k];
    rctp[i] = 1.f / fmaxf(s, 1.f);
  }
}

// ---------------- NCHW (T sliced) -> flat (T, B*N, C) ----------------
__global__ __launch_bounds__(256) void k_transpose(const float* __restrict__ x,
                                                   float* __restrict__ xf, int N) {
  __shared__ float tile[64][65];
  const int lane = threadIdx.x & 63, wave = threadIdx.x >> 6;
  const int n0 = blockIdx.x * 64, t = blockIdx.y, b = blockIdx.z;
#pragma unroll
  for (int cc = wave; cc < 64; cc += 4)
    tile[cc][lane] = x[(((size_t)b * 64 + cc) * T_IN + t) * N + n0 + lane];
  __syncthreads();
  const size_t NN = (size_t)NB * N;
#pragma unroll
  for (int nn = wave; nn < 64; nn += 4)
    xf[((size_t)t * NN + (size_t)b * N + n0 + nn) * 64 + lane] = tile[lane][nn];
}

// ---------------- MFMA GLU conv1 on property: NCHW in -> flat pf out ----------------
__global__ __launch_bounds__(256) void k_conv1_mfma(const float* __restrict__ x,
                                                    const unsigned short* __restrict__ Wb,
                                                    const float* __restrict__ bias,
                                                    float* __restrict__ pf) {
  __shared__ unsigned short xs[128][200];  // [pixel][k'], pitch 200 for banking
  const int lane = threadIdx.x & 63, wave = threadIdx.x >> 6;
  const int quad = lane >> 4, p = lane & 15;
  const int n0 = blockIdx.x * 128, t = blockIdx.y, b = blockIdx.z;
  for (int rr = wave; rr < 192; rr += 4) {
    const int i = rr & 63, kk = rr >> 6;
    const float* src = x + (((size_t)b * 64 + i) * T_IN + (t + kk)) * NPROP + n0;
    xs[lane][rr] = f2bf(src[lane]);
    xs[64 + lane][rr] = f2bf(src[64 + lane]);
  }
  __syncthreads();
  floatx4 acc[8][2];
#pragma unroll
  for (int mt = 0; mt < 8; ++mt)
#pragma unroll
    for (int nt = 0; nt < 2; ++nt) acc[mt][nt] = (floatx4){0.f, 0.f, 0.f, 0.f};
#pragma unroll
  for (int k0 = 0; k0 < 192; k0 += 32) {
    const bf16x8 b0 = *(const bf16x8*)&xs[wave * 32 + p][k0 + quad * 8];
    const bf16x8 b1 = *(const bf16x8*)&xs[wave * 32 + 16 + p][k0 + quad * 8];
#pragma unroll
    for (int mt = 0; mt < 8; ++mt) {
      const bf16x8 a = *(const bf16x8*)(Wb + (size_t)(mt * 16 + p) * 192 + k0 + quad * 8);
      acc[mt][0] = mfma16(a, b0, acc[mt][0]);
      acc[mt][1] = mfma16(a, b1, acc[mt][1]);
    }
  }
  const size_t pixbase = (size_t)t * NP + (size_t)b * NPROP + n0;
#pragma unroll
  for (int mt = 0; mt < 4; ++mt) {
    const int c0 = mt * 16 + quad * 4;
    const float4 pb = *(const float4*)(bias + c0);
    const float4 qb = *(const float4*)(bias + 64 + c0);
#pragma unroll
    for (int nt = 0; nt < 2; ++nt) {
      const int n = wave * 32 + nt * 16 + p;
      const unsigned short* xi = &xs[n][128 + c0];  // xin = tap kk=2 -> k' = 128 + c
      float4 o;
      o.x = (acc[mt][nt][0] + pb.x + bf2f(xi[0])) * sigm(acc[mt + 4][nt][0] + qb.x);
      o.y = (acc[mt][nt][1] + pb.y + bf2f(xi[1])) * sigm(acc[mt + 4][nt][1] + qb.y);
      o.z = (acc[mt][nt][2] + pb.z + bf2f(xi[2])) * sigm(acc[mt + 4][nt][2] + qb.z);
      o.w = (acc[mt][nt][3] + pb.w + bf2f(xi[3])) * sigm(acc[mt + 4][nt][3] + qb.w);
      *(float4*)(pf + (pixbase + n) * 64 + c0) = o;
    }
  }
}

// ---------------- MFMA GLU conv2 on prop: flat in (relu on read) -> fused LN -> NCHW ----------
__global__ __launch_bounds__(256) void k_conv2_mfma(const float* __restrict__ pf,
                                                    const unsigned short* __restrict__ Wb,
                                                    const float* __restrict__ bias,
                                                    const float* __restrict__ lg,
                                                    const float* __restrict__ lb,
                                                    float* __restrict__ out) {
  __shared__ unsigned short xs[128][200];
  const int lane = threadIdx.x & 63, wave = threadIdx.x >> 6;
  const int quad = lane >> 4, p = lane & 15;
  const int n0 = blockIdx.x * 128, t = blockIdx.y, b = blockIdx.z;
  const int i4 = threadIdx.x & 15, pxb = threadIdx.x >> 4;
  for (int kk = 0; kk < 3; ++kk) {
    const float* srcbase =
        pf + ((size_t)(t + kk) * NP + (size_t)b * NPROP + n0) * 64 + i4 * 4;
#pragma unroll
    for (int h = 0; h < 8; ++h) {
      const int px = h * 16 + pxb;
      const float4 v = *(const float4*)(srcbase + (size_t)px * 64);
      const unsigned a0 =
          (unsigned)f2bf(fmaxf(v.x, 0.f)) | ((unsigned)f2bf(fmaxf(v.y, 0.f)) << 16);
      const unsigned a1 =
          (unsigned)f2bf(fmaxf(v.z, 0.f)) | ((unsigned)f2bf(fmaxf(v.w, 0.f)) << 16);
      *(uint2*)&xs[px][kk * 64 + i4 * 4] = make_uint2(a0, a1);
    }
  }
  __syncthreads();
  floatx4 acc[8][2];
#pragma unroll
  for (int mt = 0; mt < 8; ++mt)
#pragma unroll
    for (int nt = 0; nt < 2; ++nt) acc[mt][nt] = (floatx4){0.f, 0.f, 0.f, 0.f};
#pragma unroll
  for (int k0 = 0; k0 < 192; k0 += 32) {
    const bf16x8 b0 = *(const bf16x8*)&xs[wave * 32 + p][k0 + quad * 8];
    const bf16x8 b1 = *(const bf16x8*)&xs[wave * 32 + 16 + p][k0 + quad * 8];
#pragma unroll
    for (int mt = 0; mt < 8; ++mt) {
      const bf16x8 a = *(const bf16x8*)(Wb + (size_t)(mt * 16 + p) * 192 + k0 + quad * 8);
      acc[mt][0] = mfma16(a, b0, acc[mt][0]);
      acc[mt][1] = mfma16(a, b1, acc[mt][1]);
    }
  }
  float o[4][2][4];
  float s1[2] = {0.f, 0.f}, s2[2] = {0.f, 0.f};
#pragma unroll
  for (int mt = 0; mt < 4; ++mt) {
    const int c0 = mt * 16 + quad * 4;
    const float4 pb = *(const float4*)(bias + c0);
    const float4 qb = *(const float4*)(bias + 64 + c0);
#pragma unroll
    for (int nt = 0; nt < 2; ++nt) {
      const int n = wave * 32 + nt * 16 + p;
      const unsigned short* xi = &xs[n][128 + c0];
      const float pbv[4] = {pb.x, pb.y, pb.z, pb.w};
      const float qbv[4] = {qb.x, qb.y, qb.z, qb.w};
#pragma unroll
      for (int r = 0; r < 4; ++r) {
        const float ov =
            (acc[mt][nt][r] + pbv[r] + bf2f(xi[r])) * sigm(acc[mt + 4][nt][r] + qbv[r]);
        o[mt][nt][r] = ov;
        s1[nt] += ov;
        s2[nt] += ov * ov;
      }
    }
  }
#pragma unroll
  for (int nt = 0; nt < 2; ++nt) {
    s1[nt] += __shfl_xor(s1[nt], 16);
    s1[nt] += __shfl_xor(s1[nt], 32);
    s2[nt] += __shfl_xor(s2[nt], 16);
    s2[nt] += __shfl_xor(s2[nt], 32);
  }
  float mean[2], rs[2];
#pragma unroll
  for (int nt = 0; nt < 2; ++nt) {
    mean[nt] = s1[nt] * (1.f / 64.f);
    const float var = s2[nt] * (1.f / 64.f) - mean[nt] * mean[nt];
    rs[nt] = rsqrtf(var + 1e-5f);
  }
#pragma unroll
  for (int mt = 0; mt < 4; ++mt) {
    const int c0 = mt * 16 + quad * 4;
    const float4 lgv = *(const float4*)(lg + c0);
    const float4 lbv = *(const float4*)(lb + c0);
    const float lgr[4] = {lgv.x, lgv.y, lgv.z, lgv.w};
    const float lbr[4] = {lbv.x, lbv.y, lbv.z, lbv.w};
#pragma unroll
    for (int nt = 0; nt < 2; ++nt) {
      const int n = wave * 32 + nt * 16 + p;
#pragma unroll
      for (int r = 0; r < 4; ++r) {
        const int c = c0 + r;
        out[(((size_t)b * 64 + c) * T2 + t) * NPROP + n0 + n] =
            (o[mt][nt][r] - mean[nt]) * rs[nt] * lgr[r] + lbr[r];
      }
    }
  }
}

// ---------------- GLU conv, N==1 tensors ----------------
__global__ __launch_bounds__(64) void k_glu_conv_small1(const float* __restrict__ x,
                                                        const float* __restrict__ W,
                                                        const float* __restrict__ bias,
                                                        float* __restrict__ xfout) {
  __shared__ float xl[192];
  const int c = threadIdx.x;
  const int t = blockIdx.x, b = blockIdx.y;
  for (int r = c; r < 192; r += 64) {
    const int i = r / 3, k = r - (r / 3) * 3;
    xl[r] = x[((size_t)b * 64 + i) * T_IN + (t + k)];
  }
  __syncthreads();
  float p = 0.f, q = 0.f;
  for (int r0 = 0; r0 < 192; r0 += 4) {
    const float4 xv = *(const float4*)(xl + r0);
    const float4 wp = *(const float4*)(W + (size_t)c * 192 + r0);
    const float4 wq = *(const float4*)(W + (size_t)(c + 64) * 192 + r0);
    p += wp.x * xv.x + wp.y * xv.y + wp.z * xv.z + wp.w * xv.w;
    q += wq.x * xv.x + wq.y * xv.y + wq.z * xv.z + wq.w * xv.w;
  }
  const float xin = xl[c * 3 + 2];
  xfout[((size_t)t * 16 + b) * 64 + c] = (p + bias[c] + xin) * sigm(q + bias[c + 64]);
}

__global__ __launch_bounds__(64) void k_glu_conv_small2(const float* __restrict__ xfin,
                                                        const float* __restrict__ W,
                                                        const float* __restrict__ bias,
                                                        const float* __restrict__ lg,
                                                        const float* __restrict__ lb,
                                                        float* __restrict__ out) {
  __shared__ float xl[192];
  const int c = threadIdx.x;
  const int t = blockIdx.x, b = blockIdx.y;
  for (int r = c; r < 192; r += 64) {
    const int i = r / 3, k = r - (r / 3) * 3;
    xl[r] = fmaxf(xfin[((size_t)(t + k) * 16 + b) * 64 + i], 0.f);
  }
  __syncthreads();
  float p = 0.f, q = 0.f;
  for (int r0 = 0; r0 < 192; r0 += 4) {
    const float4 xv = *(const float4*)(xl + r0);
    const float4 wp = *(const float4*)(W + (size_t)c * 192 + r0);
    const float4 wq = *(const float4*)(W + (size_t)(c + 64) * 192 + r0);
    p += wp.x * xv.x + wp.y * xv.y + wp.z * xv.z + wp.w * xv.w;
    q += wq.x * xv.x + wq.y * xv.y + wq.z * xv.z + wq.w * xv.w;
  }
  const float xin = xl[c * 3 + 2];
  const float o = (p + bias[c] + xin) * sigm(q + bias[c + 64]);
  float s1 = o, s2 = o * o;
#pragma unroll
  for (int off = 32; off > 0; off >>= 1) {
    s1 += __shfl_xor(s1, off);
    s2 += __shfl_xor(s2, off);
  }
  const float m = s1 * (1.f / 64.f);
  const float var = s2 * (1.f / 64.f) - m * m;
  out[((size_t)b * 64 + c) * T2 + t] = (o - m) * rsqrtf(var + 1e-5f) * lg[c] + lb[c];
}

// ---------------- MFMA: h0,h1 = rf @ gcn_W[0,1] (split-bf16, ~fp32 accurate) ----------------
__global__ __launch_bounds__(256) void k_gcn_h2(const float* __restrict__ rf,
                                                const unsigned short* __restrict__ wg,
                                                float* __restrict__ h0, float* __restrict__ h1) {
  __shared__ unsigned short xh[64][72], xl[64][72];
  const int tid = threadIdx.x;
  const int i0 = blockIdx.x * 64, t = blockIdx.y;
  {
    const int r = tid >> 2, cg = tid & 3;
    const float* src = rf + ((size_t)t * NR + i0 + r) * 64 + cg * 16;
#pragma unroll
    for (int j = 0; j < 4; ++j) {
      const float4 v = *(const float4*)(src + j * 4);
      split_store4(v, &xh[r][cg * 16 + j * 4], &xl[r][cg * 16 + j * 4]);
    }
  }
  __syncthreads();
  const int lane = tid & 63, wave = tid >> 6, quad = lane >> 4, p = lane & 15;
  floatx4 acc[2][4];
#pragma unroll
  for (int g = 0; g < 2; ++g)
#pragma unroll
    for (int mt = 0; mt < 4; ++mt) acc[g][mt] = (floatx4){0.f, 0.f, 0.f, 0.f};
#pragma unroll
  for (int k0 = 0; k0 < 64; k0 += 32) {
    const bf16x8 bh = *(const bf16x8*)&xh[wave * 16 + p][k0 + quad * 8];
    const bf16x8 bl = *(const bf16x8*)&xl[wave * 16 + p][k0 + quad * 8];
#pragma unroll
    for (int g = 0; g < 2; ++g)
#pragma unroll
      for (int mt = 0; mt < 4; ++mt) {
        const bf16x8 ah = *(const bf16x8*)(wg + g * 8192 + (size_t)(mt * 16 + p) * 64 + k0 + quad * 8);
        const bf16x8 al =
            *(const bf16x8*)(wg + g * 8192 + 4096 + (size_t)(mt * 16 + p) * 64 + k0 + quad * 8);
        acc[g][mt] = mfma16(ah, bh, acc[g][mt]);
        acc[g][mt] = mfma16(ah, bl, acc[g][mt]);
        acc[g][mt] = mfma16(al, bh, acc[g][mt]);
      }
  }
  const size_t row = (size_t)t * NR + i0 + wave * 16 + p;
#pragma unroll
  for (int mt = 0; mt < 4; ++mt) {
    *(floatx4*)(h0 + row * 64 + mt * 16 + quad * 4) = acc[0][mt];
    *(floatx4*)(h1 + row * 64 + mt * 16 + quad * 4) = acc[1][mt];
  }
}

// ---------------- edge scatters (atomics), t < 12 only ----------------
__global__ __launch_bounds__(256) void k_scatter_gcn(const int* __restrict__ src,
                                                     const int* __restrict__ dst,
                                                     const float* __restrict__ w, int E,
                                                     const float* __restrict__ h,
                                                     const float* __restrict__ dinv,
                                                     float* __restrict__ outacc) {
  const int gid = blockIdx.x * 256 + threadIdx.x;
  if (gid >= E * 192) return;
  const int cq = gid & 15;
  const int t = (gid >> 4) % 12;
  const int e = gid / 192;
  const int s = src[e], d = dst[e];
  const float nrm = dinv[s] * w[e] * dinv[d];
  const float4 hv = *(const float4*)(h + ((size_t)t * NR + s) * 64 + cq * 4);
  float* o = outacc + ((size_t)t * NR + d) * 64 + cq * 4;
  atomicAdd(o + 0, hv.x * nrm);
  atomicAdd(o + 1, hv.y * nrm);
  atomicAdd(o + 2, hv.z * nrm);
  atomicAdd(o + 3, hv.w * nrm);
}

__global__ __launch_bounds__(256) void k_scatter_sage(const int* __restrict__ src,
                                                      const int* __restrict__ dst, int E,
                                                      const float* __restrict__ xsrc, int NNsrc,
                                                      float* __restrict__ agg, int NNdst) {
  const int gid = blockIdx.x * 256 + threadIdx.x;
  if (gid >= E * 192) return;
  const int cq = gid & 15;
  const int t = (gid >> 4) % 12;
  const int e = gid / 192;
  const int s = src[e], d = dst[e];
  const float4 v = *(const float4*)(xsrc + ((size_t)t * NNsrc + s) * 64 + cq * 4);
  float* o = agg + ((size_t)t * NNdst + d) * 64 + cq * 4;
  atomicAdd(o + 0, v.x);
  atomicAdd(o + 1, v.y);
  atomicAdd(o + 2, v.z);
  atomicAdd(o + 3, v.w);
}

// ---------------- MFMA room final: GEMM + gathers + relu + LN + NCHW ----------------
__global__ __launch_bounds__(256) void k_room_f2(
    const float* __restrict__ rf, const float* __restrict__ h0, const float* __restrict__ h1,
    const float* __restrict__ aggdr, const float* __restrict__ roomg,
    const float* __restrict__ MOR, const float* __restrict__ MTR,
    const float* __restrict__ dinv0, const float* __restrict__ dinv1,
    const float* __restrict__ rcdr, const float* __restrict__ rcor,
    const float* __restrict__ rctr, const float* __restrict__ OFW,
    const float* __restrict__ TRW, const unsigned short* __restrict__ wfr,
    const float* __restrict__ bsr, const float* __restrict__ lg, const float* __restrict__ lb,
    float* __restrict__ out) {
  __shared__ unsigned short xh[64][136], xl[64][136];
  __shared__ float msA[64][17], msB[64][17];
  __shared__ float ofw_s[16][64], trw_s[16][64];
  const int tid = threadIdx.x;
  const int i0 = blockIdx.x * 64, t = blockIdx.y;
  {
    const int r = tid >> 2, cg = tid & 3;
    const size_t rowr = (size_t)t * NR + i0 + r;
    const float rca = rcdr[i0 + r];
    const float* pa = aggdr + rowr * 64 + cg * 16;
    const float* pr = rf + rowr * 64 + cg * 16;
#pragma unroll
    for (int j = 0; j < 4; ++j) {
      float4 v = *(const float4*)(pa + j * 4);
      v.x *= rca; v.y *= rca; v.z *= rca; v.w *= rca;
      split_store4(v, &xh[r][cg * 16 + j * 4], &xl[r][cg * 16 + j * 4]);
      const float4 u = *(const float4*)(pr + j * 4);
      split_store4(u, &xh[r][64 + cg * 16 + j * 4], &xl[r][64 + cg * 16 + j * 4]);
    }
    const int jm = (tid & 3) * 4;
    const float rco = rcor[i0 + r], rct = rctr[i0 + r];
    const float4 ma = *(const float4*)(MOR + (size_t)(i0 + r) * 16 + jm);
    const float4 mb = *(const float4*)(MTR + (size_t)(i0 + r) * 16 + jm);
    msA[r][jm] = ma.x * rco; msA[r][jm + 1] = ma.y * rco;
    msA[r][jm + 2] = ma.z * rco; msA[r][jm + 3] = ma.w * rco;
    msB[r][jm] = mb.x * rct; msB[r][jm + 1] = mb.y * rct;
    msB[r][jm + 2] = mb.z * rct; msB[r][jm + 3] = mb.w * rct;
  }
  ((float4*)ofw_s)[tid] = ((const float4*)(OFW + (size_t)t * 1024))[tid];
  ((float4*)trw_s)[tid] = ((const float4*)(TRW + (size_t)t * 1024))[tid];
  __syncthreads();
  const int lane = tid & 63, wave = tid >> 6, quad = lane >> 4, p = lane & 15;
  floatx4 acc[4];
#pragma unroll
  for (int mt = 0; mt < 4; ++mt) acc[mt] = (floatx4){0.f, 0.f, 0.f, 0.f};
#pragma unroll
  for (int k0 = 0; k0 < 128; k0 += 32) {
    const bf16x8 bh = *(const bf16x8*)&xh[wave * 16 + p][k0 + quad * 8];
    const bf16x8 bl = *(const bf16x8*)&xl[wave * 16 + p][k0 + quad * 8];
#pragma unroll
    for (int mt = 0; mt < 4; ++mt) {
      const bf16x8 ah = *(const bf16x8*)(wfr + (size_t)(mt * 16 + p) * 128 + k0 + quad * 8);
      const bf16x8 al = *(const bf16x8*)(wfr + 8192 + (size_t)(mt * 16 + p) * 128 + k0 + quad * 8);
      acc[mt] = mfma16(ah, bh, acc[mt]);
      acc[mt] = mfma16(ah, bl, acc[mt]);
      acc[mt] = mfma16(al, bh, acc[mt]);
    }
  }
  const int rloc = wave * 16 + p;
  const int i = i0 + rloc;
  const size_t row = (size_t)t * NR + i;
  const float d0 = dinv0[i], d1 = dinv1[i];
  const float d0sq = d0 * d0, d1sq = d1 * d1;
  float o[4][4];
#pragma unroll
  for (int mt = 0; mt < 4; ++mt) {
    const int c0 = mt * 16 + quad * 4;
    const float4 g = *(const float4*)(roomg + row * 64 + c0);
    const float4 v0 = *(const float4*)(h0 + row * 64 + c0);
    const float4 v1 = *(const float4*)(h1 + row * 64 + c0);
    const float4 bb = *(const float4*)(bsr + c0);
    o[mt][0] = acc[mt][0] + g.x + v0.x * d0sq + v1.x * d1sq + bb.x;
    o[mt][1] = acc[mt][1] + g.y + v0.y * d0sq + v1.y * d1sq + bb.y;
    o[mt][2] = acc[mt][2] + g.z + v0.z * d0sq + v1.z * d1sq + bb.z;
    o[mt][3] = acc[mt][3] + g.w + v0.w * d0sq + v1.w * d1sq + bb.w;
  }
#pragma unroll
  for (int s = 0; s < 16; ++s) {
    const float wa = msA[rloc][s], wb = msB[rloc][s];
#pragma unroll
    for (int mt = 0; mt < 4; ++mt) {
      const int c0 = mt * 16 + quad * 4;
      const float4 fa = *(const float4*)&ofw_s[s][c0];
      const float4 fb = *(const float4*)&trw_s[s][c0];
      o[mt][0] += wa * fa.x + wb * fb.x;
      o[mt][1] += wa * fa.y + wb * fb.y;
      o[mt][2] += wa * fa.z + wb * fb.z;
      o[mt][3] += wa * fa.w + wb * fb.w;
    }
  }
  float s1 = 0.f, s2 = 0.f;
#pragma unroll
  for (int mt = 0; mt < 4; ++mt)
#pragma unroll
    for (int r = 0; r < 4; ++r) {
      const float v = fmaxf(o[mt][r], 0.f);
      o[mt][r] = v;
      s1 += v;
      s2 += v * v;
    }
  s1 += __shfl_xor(s1, 16); s1 += __shfl_xor(s1, 32);
  s2 += __shfl_xor(s2, 16); s2 += __shfl_xor(s2, 32);
  const float m = s1 * (1.f / 64.f);
  const float var = s2 * (1.f / 64.f) - m * m;
  const float rs = rsqrtf(var + 1e-5f);
  const int b = i >> 8, n = i & 255;
#pragma unroll
  for (int mt = 0; mt < 4; ++mt) {
    const int c0 = mt * 16 + quad * 4;
    const float4 lgv = *(const float4*)(lg + c0);
    const float4 lbv = *(const float4*)(lb + c0);
    out[(((size_t)b * 64 + c0 + 0) * T2 + t) * NROOM + n] = (o[mt][0] - m) * rs * lgv.x + lbv.x;
    out[(((size_t)b * 64 + c0 + 1) * T2 + t) * NROOM + n] = (o[mt][1] - m) * rs * lgv.y + lbv.y;
    out[(((size_t)b * 64 + c0 + 2) * T2 + t) * NROOM + n] = (o[mt][2] - m) * rs * lgv.z + lbv.z;
    out[(((size_t)b * 64 + c0 + 3) * T2 + t) * NROOM + n] = (o[mt][3] - m) * rs * lgv.w + lbv.w;
  }
}

// ---------------- MFMA dev final: GEMM + gather + relu + LN + NCHW ----------------
__global__ __launch_bounds__(256) void k_dev_f2(
    const float* __restrict__ aggpd, const float* __restrict__ df, const float* __restrict__ MTD,
    const float* __restrict__ rcpd, const float* __restrict__ rctd,
    const float* __restrict__ TDW, const unsigned short* __restrict__ wfd,
    const float* __restrict__ bsd, const float* __restrict__ lg, const float* __restrict__ lb,
    float* __restrict__ out) {
  __shared__ unsigned short xh[64][136], xl[64][136];
  __shared__ float ms[64][17];
  __shared__ float tdw_s[16][64];
  const int tid = threadIdx.x;
  const int i0 = blockIdx.x * 64, t = blockIdx.y;
  {
    const int r = tid >> 2, cg = tid & 3;
    const size_t rowr = (size_t)t * ND + i0 + r;
    const float rca = rcpd[i0 + r];
    const float* pa = aggpd + rowr * 64 + cg * 16;
    const float* pd = df + rowr * 64 + cg * 16;
#pragma unroll
    for (int j = 0; j < 4; ++j) {
      float4 v = *(const float4*)(pa + j * 4);
      v.x *= rca; v.y *= rca; v.z *= rca; v.w *= rca;
      split_store4(v, &xh[r][cg * 16 + j * 4], &xl[r][cg * 16 + j * 4]);
      const float4 u = *(const float4*)(pd + j * 4);
      split_store4(u, &xh[r][64 + cg * 16 + j * 4], &xl[r][64 + cg * 16 + j * 4]);
    }
    const int jm = (tid & 3) * 4;
    const float rct = rctd[i0 + r];
    const float4 mv = *(const float4*)(MTD + (size_t)(i0 + r) * 16 + jm);
    ms[r][jm] = mv.x * rct; ms[r][jm + 1] = mv.y * rct;
    ms[r][jm + 2] = mv.z * rct; ms[r][jm + 3] = mv.w * rct;
  }
  ((float4*)tdw_s)[tid] = ((const float4*)(TDW + (size_t)t * 1024))[tid];
  __syncthreads();
  const int lane = tid & 63, wave = tid >> 6, quad = lane >> 4, p = lane & 15;
  floatx4 acc[4];
#pragma unroll
  for (int mt = 0; mt < 4; ++mt) acc[mt] = (floatx4){0.f, 0.f, 0.f, 0.f};
#pragma unroll
  for (int k0 = 0; k0 < 128; k0 += 32) {
    const bf16x8 bh = *(const bf16x8*)&xh[wave * 16 + p][k0 + quad * 8];
    const bf16x8 bl = *(const bf16x8*)&xl[wave * 16 + p][k0 + quad * 8];
#pragma unroll
    for (int mt = 0; mt < 4; ++mt) {
      const bf16x8 ah = *(const bf16x8*)(wfd + (size_t)(mt * 16 + p) * 128 + k0 + quad * 8);
      const bf16x8 al = *(const bf16x8*)(wfd + 8192 + (size_t)(mt * 16 + p) * 128 + k0 + quad * 8);
      acc[mt] = mfma16(ah, bh, acc[mt]);
      acc[mt] = mfma16(ah, bl, acc[mt]);
      acc[mt] = mfma16(al, bh, acc[mt]);
    }
  }
  const int rloc = wave * 16 + p;
  const int i = i0 + rloc;
  float o[4][4];
#pragma unroll
  for (int mt = 0; mt < 4; ++mt) {
    const int c0 = mt * 16 + quad * 4;
    const float4 bb = *(const float4*)(bsd + c0);
    o[mt][0] = acc[mt][0] + bb.x;
    o[mt][1] = acc[mt][1] + bb.y;
    o[mt][2] = acc[mt][2] + bb.z;
    o[mt][3] = acc[mt][3] + bb.w;
  }
#pragma unroll
  for (int s = 0; s < 16; ++s) {
    const float w = ms[rloc][s];
#pragma unroll
    for (int mt = 0; mt < 4; ++mt) {
      const int c0 = mt * 16 + quad * 4;
      const float4 f = *(const float4*)&tdw_s[s][c0];
      o[mt][0] += w * f.x; o[mt][1] += w * f.y; o[mt][2] += w * f.z; o[mt][3] += w * f.w;
    }
  }
  float s1 = 0.f, s2 = 0.f;
#pragma unroll
  for (int mt = 0; mt < 4; ++mt)
#pragma unroll
    for (int r = 0; r < 4; ++r) {
      const float v = fmaxf(o[mt][r], 0.f);
      o[mt][r] = v;
      s1 += v;
      s2 += v * v;
    }
  s1 += __shfl_xor(s1, 16); s1 += __shfl_xor(s1, 32);
  s2 += __shfl_xor(s2, 16); s2 += __shfl_xor(s2, 32);
  const float m = s1 * (1.f / 64.f);
  const float var = s2 * (1.f / 64.f) - m * m;
  const float rs = rsqrtf(var + 1e-5f);
  const int b = i >> 10, n = i & 1023;
#pragma unroll
  for (int mt = 0; mt < 4; ++mt) {
    const int c0 = mt * 16 + quad * 4;
    const float4 lgv = *(const float4*)(lg + c0);
    const float4 lbv = *(const float4*)(lb + c0);
    out[(((size_t)b * 64 + c0 + 0) * T2 + t) * NDEV + n] = (o[mt][0] - m) * rs * lgv.x + lbv.x;
    out[(((size_t)b * 64 + c0 + 1) * T2 + t) * NDEV + n] = (o[mt][1] - m) * rs * lgv.y + lbv.y;
    out[(((size_t)b * 64 + c0 + 2) * T2 + t) * NDEV + n] = (o[mt][2] - m) * rs * lgv.z + lbv.z;
    out[(((size_t)b * 64 + c0 + 3) * T2 + t) * NDEV + n] = (o[mt][3] - m) * rs * lgv.w + lbv.w;
  }
}

// ---------------- MFMA prop final: pf = pf@Wr5 + gather@Wl5 + bl5 (in-place) ----------------
__global__ __launch_bounds__(256) void k_prop_f2(float* __restrict__ pf,
                                                 const float* __restrict__ MTP,
                                                 const float* __restrict__ rctp,
                                                 const float* __restrict__ TPW,
                                                 const unsigned short* __restrict__ wfp,
                                                 const float* __restrict__ bl5) {
  __shared__ unsigned short xh[64][72], xl[64][72];
  __shared__ float ms[64][17];
  __shared__ float tpw_s[16][64];
  const int tid = threadIdx.x;
  const int i0 = blockIdx.x * 64, t = blockIdx.y;
  {
    const int r = tid >> 2, cg = tid & 3;
    const float* src = pf + ((size_t)t * NP + i0 + r) * 64 + cg * 16;
#pragma unroll
    for (int j = 0; j < 4; ++j) {
      const float4 v = *(const float4*)(src + j * 4);
      split_store4(v, &xh[r][cg * 16 + j * 4], &xl[r][cg * 16 + j * 4]);
    }
    const int jm = (tid & 3) * 4;
    const float rct = rctp[i0 + r];
    const float4 mv = *(const float4*)(MTP + (size_t)(i0 + r) * 16 + jm);
    ms[r][jm] = mv.x * rct; ms[r][jm + 1] = mv.y * rct;
    ms[r][jm + 2] = mv.z * rct; ms[r][jm + 3] = mv.w * rct;
  }
  ((float4*)tpw_s)[tid] = ((const float4*)(TPW + (size_t)t * 1024))[tid];
  __syncthreads();
  const int lane = tid & 63, wave = tid >> 6, quad = lane >> 4, p = lane & 15;
  floatx4 acc[4];
#pragma unroll
  for (int mt = 0; mt < 4; ++mt) acc[mt] = (floatx4){0.f, 0.f, 0.f, 0.f};
#pragma unroll
  for (int k0 = 0; k0 < 64; k0 += 32) {
    const bf16x8 bh = *(const bf16x8*)&xh[wave * 16 + p][k0 + quad * 8];
    const bf16x8 bl = *(const bf16x8*)&xl[wave * 16 + p][k0 + quad * 8];
#pragma unroll
    for (int mt = 0; mt < 4; ++mt) {
      const bf16x8 ah = *(const bf16x8*)(wfp + (size_t)(mt * 16 + p) * 64 + k0 + quad * 8);
      const bf16x8 al = *(const bf16x8*)(wfp + 4096 + (size_t)(mt * 16 + p) * 64 + k0 + quad * 8);
      acc[mt] = mfma16(ah, bh, acc[mt]);
      acc[mt] = mfma16(ah, bl, acc[mt]);
      acc[mt] = mfma16(al, bh, acc[mt]);
    }
  }
  const int rloc = wave * 16 + p;
  float o[4][4];
#pragma unroll
  for (int mt = 0; mt < 4; ++mt) {
    const int c0 = mt * 16 + quad * 4;
    const float4 bb = *(const float4*)(bl5 + c0);
    o[mt][0] = acc[mt][0] + bb.x;
    o[mt][1] = acc[mt][1] + bb.y;
    o[mt][2] = acc[mt][2] + bb.z;
    o[mt][3] = acc[mt][3] + bb.w;
  }
#pragma unroll
  for (int s = 0; s < 16; ++s) {
    const float w = ms[rloc][s];
#pragma unroll
    for (int mt = 0; mt < 4; ++mt) {
      const int c0 = mt * 16 + quad * 4;
      const float4 f = *(const float4*)&tpw_s[s][c0];
      o[mt][0] += w * f.x; o[mt][1] += w * f.y; o[mt][2] += w * f.z; o[mt][3] += w * f.w;
    }
  }
  const size_t row = (size_t)t * NP + i0 + rloc;
#pragma unroll
  for (int mt = 0; mt < 4; ++mt) {
    const int c0 = mt * 16 + quad * 4;
    float4 st;
    st.x = o[mt][0]; st.y = o[mt][1]; st.z = o[mt][2]; st.w = o[mt][3];
    *(float4*)(pf + row * 64 + c0) = st;
  }
}

// ---------------- host launcher ----------------
extern "C" void kernel_launch(void* const* d_in, const int* in_sizes, int n_in, void* d_out,
                              int out_size, void* d_ws, size_t ws_size, hipStream_t stream) {
  (void)n_in; (void)out_size; (void)ws_size;
  const float* x_room = (const float*)d_in[0];
  const float* x_device = (const float*)d_in[1];
  const float* x_property = (const float*)d_in[2];
  const float* x_outside = (const float*)d_in[3];
  const float* x_time = (const float*)d_in[4];
  const float* conv1_W = (const float*)d_in[5];
  const float* conv1_b = (const float*)d_in[6];
  const float* conv2_W = (const float*)d_in[7];
  const float* conv2_b = (const float*)d_in[8];
  const float* gcn_W = (const float*)d_in[9];
  const float* gcn_b = (const float*)d_in[10];
  const float* sage_Wl = (const float*)d_in[11];
  const float* sage_bl = (const float*)d_in[12];
  const float* sage_Wr = (const float*)d_in[13];
  const float* ln_g = (const float*)d_in[14];
  const float* ln_b = (const float*)d_in[15];
  const float* hh_w = (const float*)d_in[16];
  const float* hv_w = (const float*)d_in[17];
  const int* hh_src = (const int*)d_in[18];
  const int* hh_dst = (const int*)d_in[19];
  const int* hv_src = (const int*)d_in[20];
  const int* hv_dst = (const int*)d_in[21];
  const int* dr_src = (const int*)d_in[22];
  const int* dr_dst = (const int*)d_in[23];
  const int* pd_src = (const int*)d_in[24];
  const int* pd_dst = (const int*)d_in[25];
  const int* or_src = (const int*)d_in[26];
  const int* or_dst = (const int*)d_in[27];
  const int* tr_src = (const int*)d_in[28];
  const int* tr_dst = (const int*)d_in[29];
  const int* td_src = (const int*)d_in[30];
  const int* td_dst = (const int*)d_in[31];
  const int* tp_src = (const int*)d_in[32];
  const int* tp_dst = (const int*)d_in[33];
  const int E_hh = in_sizes[18], E_hv = in_sizes[20], E_dr = in_sizes[22], E_pd = in_sizes[24];
  const int E_or = in_sizes[26], E_tr = in_sizes[28], E_td = in_sizes[30], E_tp = in_sizes[32];

  float* ws = (float*)d_ws;
  float* out = (float*)d_out;
  unsigned short* wb1 = (unsigned short*)(ws + O_WB1);
  unsigned short* wb2 = (unsigned short*)(ws + O_WB2);
  unsigned short* wfd = (unsigned short*)(ws + O_WFD);
  unsigned short* wfr = (unsigned short*)(ws + O_WFR);
  unsigned short* wfp = (unsigned short*)(ws + O_WFP);
  unsigned short* wg  = (unsigned short*)(ws + O_WG);

  hipMemsetAsync(ws + O_ZERO, 0, ZERO_CNT * sizeof(float), stream);

  k_prep<<<16, 256, 0, stream>>>(sage_Wr, gcn_b, sage_bl, ws + O_WSR, ws + O_WSD, ws + O_BSR,
                                 ws + O_BSD);
  k_wbf<<<96, 256, 0, stream>>>(conv1_W, conv2_W, wb1, wb2);
  k_wfin<<<112, 256, 0, stream>>>(sage_Wl, sage_Wr, gcn_W, ws + O_WSR, ws + O_WSD, wfd, wfr, wfp,
                                  wg);

  k_count_w<<<(E_hh + 255) / 256, 256, 0, stream>>>(hh_dst, hh_w, E_hh, ws + O_DEG0);
  k_count_w<<<(E_hv + 255) / 256, 256, 0, stream>>>(hv_dst, hv_w, E_hv, ws + O_DEG1);
  k_count1<<<(E_dr + 255) / 256, 256, 0, stream>>>(dr_dst, E_dr, ws + O_CNTDR);
  k_count1<<<(E_pd + 255) / 256, 256, 0, stream>>>(pd_dst, E_pd, ws + O_CNTPD);
  k_cmat<<<(E_or + 255) / 256, 256, 0, stream>>>(or_src, or_dst, E_or, ws + O_MOR);
  k_cmat<<<(E_tr + 255) / 256, 256, 0, stream>>>(tr_src, tr_dst, E_tr, ws + O_MTR);
  k_cmat<<<(E_td + 255) / 256, 256, 0, stream>>>(td_src, td_dst, E_td, ws + O_MTD);
  k_cmat<<<(E_tp + 255) / 256, 256, 0, stream>>>(tp_src, tp_dst, E_tp, ws + O_MTP);
  k_finalize<<<256, 256, 0, stream>>>(ws + O_DEG0, ws + O_DEG1, ws + O_CNTDR, ws + O_CNTPD,
                                      ws + O_MOR, ws + O_MTR, ws + O_MTD, ws + O_MTP,
                                      ws + O_DINV0, ws + O_DINV1, ws + O_RCDR, ws + O_RCOR,
                                      ws + O_RCTR, ws + O_RCPD, ws + O_RCTD, ws + O_RCTP);

  // rf/df only consumed at t < T2
  k_transpose<<<dim3(NROOM / 64, T2, NB), 256, 0, stream>>>(x_room, ws + O_RF, NROOM);
  k_transpose<<<dim3(NDEV / 64, T2, NB), 256, 0, stream>>>(x_device, ws + O_DF, NDEV);

  // GLU conv1 (MFMA for prop, scalar for N==1 tensors) — prop needs all 14 t (conv2 taps)
  k_conv1_mfma<<<dim3(NPROP / 128, T1, NB), 256, 0, stream>>>(x_property, wb1, conv1_b,
                                                              ws + O_PF);
  k_glu_conv_small1<<<dim3(T1, NB), 64, 0, stream>>>(x_outside, conv1_W + 128 * 192,
                                                     conv1_b + 128, ws + O_OF);
  k_glu_conv_small1<<<dim3(T1, NB), 64, 0, stream>>>(x_time, conv1_W + 2 * 128 * 192,
                                                     conv1_b + 2 * 128, ws + O_TF);
  k_wprod<<<224, 256, 0, stream>>>(ws + O_OF, ws + O_TF, sage_Wl, ws + O_OFW);

  k_gcn_h2<<<dim3(NR / 64, T2), 256, 0, stream>>>(ws + O_RF, wg, ws + O_H0, ws + O_H1);
  k_scatter_gcn<<<(E_hh * 192 + 255) / 256, 256, 0, stream>>>(hh_src, hh_dst, hh_w, E_hh,
                                                              ws + O_H0, ws + O_DINV0,
                                                              ws + O_ROOMG);
  k_scatter_gcn<<<(E_hv * 192 + 255) / 256, 256, 0, stream>>>(hv_src, hv_dst, hv_w, E_hv,
                                                              ws + O_H1, ws + O_DINV1,
                                                              ws + O_ROOMG);
  k_scatter_sage<<<(E_dr * 192 + 255) / 256, 256, 0, stream>>>(dr_src, dr_dst, E_dr, ws + O_DF,
                                                               ND, ws + O_AGGDR, NR);
  k_scatter_sage<<<(E_pd * 192 + 255) / 256, 256, 0, stream>>>(pd_src, pd_dst, E_pd, ws + O_PF,
                                                               NP, ws + O_AGGPD, ND);

  k_room_f2<<<dim3(NR / 64, T2), 256, 0, stream>>>(
      ws + O_RF, ws + O_H0, ws + O_H1, ws + O_AGGDR, ws + O_ROOMG, ws + O_MOR, ws + O_MTR,
      ws + O_DINV0, ws + O_DINV1, ws + O_RCDR, ws + O_RCOR, ws + O_RCTR, ws + O_OFW, ws + O_TRW,
      wfr, ws + O_BSR, ln_g, ln_b, out + OUT_ROOM);
  k_dev_f2<<<dim3(ND / 64, T2), 256, 0, stream>>>(
      ws + O_AGGPD, ws + O_DF, ws + O_MTD, ws + O_RCPD, ws + O_RCTD, ws + O_TDW, wfd, ws + O_BSD,
      ln_g + 64, ln_b + 64, out + OUT_DEV);
  k_prop_f2<<<dim3(NP / 64, T1), 256, 0, stream>>>(ws + O_PF, ws + O_MTP, ws + O_RCTP,
                                                   ws + O_TPW, wfp, sage_bl + 5 * 64);

  k_conv2_mfma<<<dim3(NPROP / 128, T2, NB), 256, 0, stream>>>(
      ws + O_PF, wb2, conv2_b, ln_g + 2 * 64, ln_b + 2 * 64, out + OUT_PROP);
  k_glu_conv_small2<<<dim3(T2, NB), 64, 0, stream>>>(ws + O_OF, conv2_W + 128 * 192,
                                                     conv2_b + 128, ln_g + 3 * 64, ln_b + 3 * 64,
                                                     out + OUT_OUT);
  k_glu_conv_small2<<<dim3(T2, NB), 64, 0, stream>>>(ws + O_TF, conv2_W + 2 * 128 * 192,
                                                     conv2_b + 2 * 128, ln_g + 4 * 64,
                                                     ln_b + 4 * 64, out + OUT_TIME);
}

// Round 3
// 1586.246 us; speedup vs baseline: 3.1955x; 1.5728x over previous
//
#include <hip/hip_runtime.h>
#include <math.h>

// ---------------- problem constants ----------------
#define T_IN  16
#define T1    14
#define T2    12
#define NB    16
#define NPROP 4096
#define NDEV  1024
#define NROOM 256
#define NR    4096    // B*N_ROOM
#define ND    16384   // B*N_DEV
#define NP    65536   // B*N_PROP
// B*N_OUT = B*N_TIME = 16

// ---------------- workspace layout (floats) ----------------
constexpr size_t SZ_PF = (size_t)T1 * NP * 64;   // 58,720,256
constexpr size_t SZ_DF = (size_t)T1 * ND * 64;   // 14,680,064
constexpr size_t SZ_RF = (size_t)T1 * NR * 64;   //  3,670,016
constexpr size_t SZ_OF = (size_t)T1 * 16 * 64;   //     14,336

constexpr size_t O_PF   = 0;
constexpr size_t O_DF   = O_PF + SZ_PF;
constexpr size_t O_RF   = O_DF + SZ_DF;
constexpr size_t O_H0   = O_RF + SZ_RF;
constexpr size_t O_H1   = O_H0 + SZ_RF;
constexpr size_t O_OF   = O_H1 + SZ_RF;
constexpr size_t O_TF   = O_OF + SZ_OF;
constexpr size_t O_WSR  = O_TF + SZ_OF;      // Wr0+Wr2+Wr3 (4096)
constexpr size_t O_WSD  = O_WSR + 4096;      // Wr1+Wr4     (4096)
constexpr size_t O_BSR  = O_WSD + 4096;      // summed room bias (64)
constexpr size_t O_BSD  = O_BSR + 64;        // summed dev bias  (64)
constexpr size_t O_DINV0= O_BSD + 64;
constexpr size_t O_DINV1= O_DINV0 + 4096;
constexpr size_t O_RCDR = O_DINV1 + 4096;
constexpr size_t O_RCOR = O_RCDR + 4096;
constexpr size_t O_RCTR = O_RCOR + 4096;
constexpr size_t O_RCPD = O_RCTR + 4096;
constexpr size_t O_RCTD = O_RCPD + 16384;
constexpr size_t O_RCTP = O_RCTD + 16384;
// bf16 conv weights, k-permuted (k' = kk*64 + i): [128][192] shorts each
constexpr size_t O_WB1  = O_RCTP + 65536;    // 24576 shorts = 12288 float slots
constexpr size_t O_WB2  = O_WB1 + 12288;
// split-bf16 transposed weight arrays for the final GEMMs (hi then lo)
constexpr size_t O_WFD  = O_WB2 + 12288;     // dev  [64][128] hi+lo
constexpr size_t O_WFR  = O_WFD + 8192;      // room [64][128] hi+lo
constexpr size_t O_WFP  = O_WFR + 8192;      // prop [64][64]  hi+lo
constexpr size_t O_WG   = O_WFP + 4096;      // gcn g0,g1 each [64][64] hi+lo
// precomputed (tf/of @ Wl) products, fp32: [14][16][64] each
constexpr size_t O_OFW  = O_WG + 8192;       // of @ Wl2
constexpr size_t O_TRW  = O_OFW + 14336;     // tf @ Wl3
constexpr size_t O_TDW  = O_TRW + 14336;     // tf @ Wl4
constexpr size_t O_TPW  = O_TDW + 14336;     // tf @ Wl5
// CSR structures (ints stored in float slots)
constexpr size_t O_HHRP = O_TPW + 14336;     // 4097 -> 4160
constexpr size_t O_HHCUR= O_HHRP + 4160;     // 4096
constexpr size_t O_HHCOL= O_HHCUR + 4096;    // 16384
constexpr size_t O_HHWN = O_HHCOL + 16384;   // 16384 (float)
constexpr size_t O_HVRP = O_HHWN + 16384;    // 4160
constexpr size_t O_HVCUR= O_HVRP + 4160;     // 4096
constexpr size_t O_HVCOL= O_HVCUR + 4096;    // 8192
constexpr size_t O_HVWN = O_HVCOL + 8192;    // 8192 (float)
constexpr size_t O_DRRP = O_HVWN + 8192;     // 4160
constexpr size_t O_DRCUR= O_DRRP + 4160;     // 4096
constexpr size_t O_DRCOL= O_DRCUR + 4096;    // 16384
constexpr size_t O_PDRP = O_DRCOL + 16384;   // 16385 -> 16448
constexpr size_t O_PDCUR= O_PDRP + 16448;    // 16384
constexpr size_t O_PDCOL= O_PDCUR + 16384;   // 65536
// ---- zero-initialized region starts here ----
constexpr size_t O_ZERO  = O_PDCOL + 65536;
constexpr size_t O_DEG0  = O_ZERO;                    // 4096 (float, weighted)
constexpr size_t O_DEG1  = O_DEG0 + 4096;             // 4096 (float)
constexpr size_t O_CNTDR = O_DEG1 + 4096;             // 4096 (int)
constexpr size_t O_CNTPD = O_CNTDR + 4096;            // 16384 (int)
constexpr size_t O_CHH   = O_CNTPD + 16384;           // 4096 (int)
constexpr size_t O_CHV   = O_CHH + 4096;              // 4096 (int)
constexpr size_t O_MOR   = O_CHV + 4096;              // 4096 x 16
constexpr size_t O_MTR   = O_MOR + 65536;             // 4096 x 16
constexpr size_t O_MTD   = O_MTR + 65536;             // 16384 x 16
constexpr size_t O_MTP   = O_MTD + 262144;            // 65536 x 16
constexpr size_t O_END   = O_MTP + 1048576;
constexpr size_t ZERO_CNT = O_END - O_ZERO;

// output (floats) offsets in d_out (NCHW, concatenated in return order)
constexpr size_t OUT_ROOM = 0;
constexpr size_t OUT_DEV  = 3145728;
constexpr size_t OUT_PROP = 15728640;
constexpr size_t OUT_OUT  = 66060288;
constexpr size_t OUT_TIME = 66072576;

__device__ __forceinline__ float sigm(float x) { return 1.f / (1.f + __expf(-x)); }

__device__ __forceinline__ unsigned short f2bf(float f) {
  unsigned u = __float_as_uint(f);
  u += 0x7fffu + ((u >> 16) & 1u);
  return (unsigned short)(u >> 16);
}
__device__ __forceinline__ float bf2f(unsigned short h) {
  return __uint_as_float(((unsigned)h) << 16);
}

typedef __attribute__((ext_vector_type(8))) short bf16x8;
typedef __attribute__((ext_vector_type(4))) float floatx4;

__device__ __forceinline__ floatx4 mfma16(bf16x8 a, bf16x8 b, floatx4 c) {
  return __builtin_amdgcn_mfma_f32_16x16x32_bf16(a, b, c, 0, 0, 0);
}

// split a float4 into bf16 hi + bf16 lo (x ~= hi + lo), store 8B each
__device__ __forceinline__ void split_store4(float4 v, unsigned short* ph, unsigned short* pl) {
  const unsigned short h0 = f2bf(v.x), h1 = f2bf(v.y), h2 = f2bf(v.z), h3 = f2bf(v.w);
  *(uint2*)ph = make_uint2((unsigned)h0 | ((unsigned)h1 << 16),
                           (unsigned)h2 | ((unsigned)h3 << 16));
  const unsigned short l0 = f2bf(v.x - bf2f(h0)), l1 = f2bf(v.y - bf2f(h1));
  const unsigned short l2 = f2bf(v.z - bf2f(h2)), l3 = f2bf(v.w - bf2f(h3));
  *(uint2*)pl = make_uint2((unsigned)l0 | ((unsigned)l1 << 16),
                           (unsigned)l2 | ((unsigned)l3 << 16));
}

// ---------------- small prep kernels ----------------
__global__ void k_prep(const float* __restrict__ sWr, const float* __restrict__ gcnb,
                       const float* __restrict__ sbl, float* __restrict__ Wsr,
                       float* __restrict__ Wsd, float* __restrict__ bsr, float* __restrict__ bsd) {
  const int k = blockIdx.x * 256 + threadIdx.x;
  if (k < 4096) {
    Wsr[k] = sWr[k] + sWr[2 * 4096 + k] + sWr[3 * 4096 + k];
    Wsd[k] = sWr[4096 + k] + sWr[4 * 4096 + k];
  }
  if (k < 64) {
    bsr[k] = gcnb[k] + gcnb[64 + k] + sbl[k] + sbl[2 * 64 + k] + sbl[3 * 64 + k];
    bsd[k] = sbl[64 + k] + sbl[4 * 64 + k];
  }
}

// convert prop conv weights (conv index 0) to bf16 with k' = kk*64 + i ordering
__global__ void k_wbf(const float* __restrict__ W1, const float* __restrict__ W2,
                      unsigned short* __restrict__ wb1, unsigned short* __restrict__ wb2) {
  const int idx = blockIdx.x * 256 + threadIdx.x;
  if (idx >= 128 * 192) return;
  const int o = idx / 192, kp = idx % 192;
  const int kk = kp >> 6, i = kp & 63;
  const size_t srcoff = (size_t)o * 192 + i * 3 + kk;
  wb1[idx] = f2bf(W1[srcoff]);
  wb2[idx] = f2bf(W2[srcoff]);
}

// build split-bf16 transposed weight arrays: A[o][k] layout for MFMA A-fragments
__global__ void k_wfin(const float* __restrict__ sWl, const float* __restrict__ sWr,
                       const float* __restrict__ gcnW, const float* __restrict__ Wsr,
                       const float* __restrict__ Wsd, unsigned short* __restrict__ wfd,
                       unsigned short* __restrict__ wfr, unsigned short* __restrict__ wfp,
                       unsigned short* __restrict__ wg) {
  const int idx = blockIdx.x * 256 + threadIdx.x;
  if (idx >= 28672) return;
  float w;
  unsigned short* hi;
  unsigned short* lo;
  if (idx < 8192) {  // dev: [Wl1 ; Wsd]
    const int o = idx >> 7, k = idx & 127;
    w = (k < 64) ? sWl[4096 + k * 64 + o] : Wsd[(k - 64) * 64 + o];
    hi = wfd + idx;
    lo = wfd + 8192 + idx;
  } else if (idx < 16384) {  // room: [Wl0 ; Wsr]
    const int j = idx - 8192;
    const int o = j >> 7, k = j & 127;
    w = (k < 64) ? sWl[k * 64 + o] : Wsr[(k - 64) * 64 + o];
    hi = wfr + j;
    lo = wfr + 8192 + j;
  } else if (idx < 20480) {  // prop: Wr5
    const int j = idx - 16384;
    const int o = j >> 6, k = j & 63;
    w = sWr[5 * 4096 + k * 64 + o];
    hi = wfp + j;
    lo = wfp + 4096 + j;
  } else {  // gcn W0, W1
    const int j = idx - 20480;
    const int g = j >> 12, jj = j & 4095;
    const int o = jj >> 6, k = jj & 63;
    w = gcnW[g * 4096 + k * 64 + o];
    hi = wg + g * 8192 + jj;
    lo = wg + g * 8192 + 4096 + jj;
  }
  const unsigned short h = f2bf(w);
  *hi = h;
  *lo = f2bf(w - bf2f(h));
}

// precompute (of|tf)[t][s] @ Wl{2,3,4,5} in fp32: outputs [l][14][16][64]
__global__ void k_wprod(const float* __restrict__ of, const float* __restrict__ tf,
                        const float* __restrict__ sWl, float* __restrict__ dstbase) {
  const int idx = blockIdx.x * 256 + threadIdx.x;  // 57344 total
  const int d = idx & 63, l = (idx >> 6) & 3, s = (idx >> 8) & 15, t = idx >> 12;
  if (t >= 14) return;
  const float* v = (l == 0 ? of : tf) + ((size_t)t * 16 + s) * 64;
  const float* W = sWl + (size_t)(l + 2) * 4096;
  float a = 0.f;
  for (int c = 0; c < 64; ++c) a += v[c] * W[c * 64 + d];
  dstbase[(size_t)l * 14336 + ((size_t)t * 16 + s) * 64 + d] = a;
}

__global__ void k_count_w(const int* __restrict__ dst, const float* __restrict__ w, int E,
                          float* __restrict__ deg) {
  const int e = blockIdx.x * 256 + threadIdx.x;
  if (e < E) atomicAdd(&deg[dst[e]], w[e]);
}
__global__ void k_counti(const int* __restrict__ dst, int E, int* __restrict__ cnt) {
  const int e = blockIdx.x * 256 + threadIdx.x;
  if (e < E) atomicAdd(&cnt[dst[e]], 1);
}
__global__ void k_cmat(const int* __restrict__ src, const int* __restrict__ dst, int E,
                       float* __restrict__ M) {
  const int e = blockIdx.x * 256 + threadIdx.x;
  if (e < E) atomicAdd(&M[(size_t)dst[e] * 16 + src[e]], 1.f);
}

__global__ void k_finalize(const float* __restrict__ deg0, const float* __restrict__ deg1,
                           const int* __restrict__ cntdr, const int* __restrict__ cntpd,
                           const float* __restrict__ MOR, const float* __restrict__ MTR,
                           const float* __restrict__ MTD, const float* __restrict__ MTP,
                           float* __restrict__ dinv0, float* __restrict__ dinv1,
                           float* __restrict__ rcdr, float* __restrict__ rcor,
                           float* __restrict__ rctr, float* __restrict__ rcpd,
                           float* __restrict__ rctd, float* __restrict__ rctp) {
  const int i = blockIdx.x * 256 + threadIdx.x;  // 65536 threads
  if (i < 4096) {
    dinv0[i] = rsqrtf(deg0[i] + 1.f);   // +1 = self-loop weight
    dinv1[i] = rsqrtf(deg1[i] + 1.f);
    rcdr[i] = 1.f / fmaxf((float)cntdr[i], 1.f);
    float s0 = 0.f, s1 = 0.f;
    for (int s = 0; s < 16; ++s) { s0 += MOR[i * 16 + s]; s1 += MTR[i * 16 + s]; }
    rcor[i] = 1.f / fmaxf(s0, 1.f);
    rctr[i] = 1.f / fmaxf(s1, 1.f);
  }
  if (i < 16384) {
    rcpd[i] = 1.f / fmaxf((float)cntpd[i], 1.f);
    float s = 0.f;
    for (int k = 0; k < 16; ++k) s += MTD[i * 16 + k];
    rctd[i] = 1.f / fmaxf(s, 1.f);
  }
  {
    float s = 0.f;
    for (int k = 0; k < 16; ++k) s += MTP[(size_t)i * 16 + k];
    rctp[i] = 1.f / fmaxf(s, 1.f);
  }
}

// single-block exclusive scan of n counts -> rowptr[n+1], cursor[n] (n multiple of 256)
__global__ __launch_bounds__(256) void k_scan(const int* __restrict__ cnt, int n,
                                              int* __restrict__ rowptr,
                                              int* __restrict__ cursor) {
  __shared__ int tsum[256];
  const int tid = threadIdx.x;
  const int per = n >> 8;
  int s = 0;
  for (int j = 0; j < per; ++j) s += cnt[tid * per + j];
  tsum[tid] = s;
  __syncthreads();
  for (int off = 1; off < 256; off <<= 1) {
    int v = (tid >= off) ? tsum[tid - off] : 0;
    __syncthreads();
    tsum[tid] += v;
    __syncthreads();
  }
  int base = (tid == 0) ? 0 : tsum[tid - 1];
  for (int j = 0; j < per; ++j) {
    const int idx = tid * per + j;
    rowptr[idx] = base;
    cursor[idx] = base;
    base += cnt[idx];
  }
  if (tid == 255) rowptr[n] = base;
}

__global__ void k_fill(const int* __restrict__ src, const int* __restrict__ dst, int E,
                       int* __restrict__ cursor, int* __restrict__ col) {
  const int e = blockIdx.x * 256 + threadIdx.x;
  if (e < E) {
    const int pos = atomicAdd(&cursor[dst[e]], 1);
    col[pos] = src[e];
  }
}
__global__ void k_fill_w(const int* __restrict__ src, const int* __restrict__ dst,
                         const float* __restrict__ w, int E, const float* __restrict__ dinv,
                         int* __restrict__ cursor, int* __restrict__ col,
                         float* __restrict__ wn) {
  const int e = blockIdx.x * 256 + threadIdx.x;
  if (e < E) {
    const int s = src[e], d = dst[e];
    const int pos = atomicAdd(&cursor[d], 1);
    col[pos] = s;
    wn[pos] = dinv[s] * w[e] * dinv[d];
  }
}

// ---------------- NCHW (T sliced) -> flat (T, B*N, C) ----------------
__global__ __launch_bounds__(256) void k_transpose(const float* __restrict__ x,
                                                   float* __restrict__ xf, int N) {
  __shared__ float tile[64][65];
  const int lane = threadIdx.x & 63, wave = threadIdx.x >> 6;
  const int n0 = blockIdx.x * 64, t = blockIdx.y, b = blockIdx.z;
#pragma unroll
  for (int cc = wave; cc < 64; cc += 4)
    tile[cc][lane] = x[(((size_t)b * 64 + cc) * T_IN + t) * N + n0 + lane];
  __syncthreads();
  const size_t NN = (size_t)NB * N;
#pragma unroll
  for (int nn = wave; nn < 64; nn += 4)
    xf[((size_t)t * NN + (size_t)b * N + n0 + nn) * 64 + lane] = tile[lane][nn];
}

// ---------------- MFMA GLU conv1 on property: NCHW in -> flat pf out ----------------
__global__ __launch_bounds__(256) void k_conv1_mfma(const float* __restrict__ x,
                                                    const unsigned short* __restrict__ Wb,
                                                    const float* __restrict__ bias,
                                                    float* __restrict__ pf) {
  __shared__ unsigned short xs[128][200];  // [pixel][k'], pitch 200 for banking
  const int lane = threadIdx.x & 63, wave = threadIdx.x >> 6;
  const int quad = lane >> 4, p = lane & 15;
  const int n0 = blockIdx.x * 128, t = blockIdx.y, b = blockIdx.z;
  for (int rr = wave; rr < 192; rr += 4) {
    const int i = rr & 63, kk = rr >> 6;
    const float* src = x + (((size_t)b * 64 + i) * T_IN + (t + kk)) * NPROP + n0;
    xs[lane][rr] = f2bf(src[lane]);
    xs[64 + lane][rr] = f2bf(src[64 + lane]);
  }
  __syncthreads();
  floatx4 acc[8][2];
#pragma unroll
  for (int mt = 0; mt < 8; ++mt)
#pragma unroll
    for (int nt = 0; nt < 2; ++nt) acc[mt][nt] = (floatx4){0.f, 0.f, 0.f, 0.f};
#pragma unroll
  for (int k0 = 0; k0 < 192; k0 += 32) {
    const bf16x8 b0 = *(const bf16x8*)&xs[wave * 32 + p][k0 + quad * 8];
    const bf16x8 b1 = *(const bf16x8*)&xs[wave * 32 + 16 + p][k0 + quad * 8];
#pragma unroll
    for (int mt = 0; mt < 8; ++mt) {
      const bf16x8 a = *(const bf16x8*)(Wb + (size_t)(mt * 16 + p) * 192 + k0 + quad * 8);
      acc[mt][0] = mfma16(a, b0, acc[mt][0]);
      acc[mt][1] = mfma16(a, b1, acc[mt][1]);
    }
  }
  const size_t pixbase = (size_t)t * NP + (size_t)b * NPROP + n0;
#pragma unroll
  for (int mt = 0; mt < 4; ++mt) {
    const int c0 = mt * 16 + quad * 4;
    const float4 pb = *(const float4*)(bias + c0);
    const float4 qb = *(const float4*)(bias + 64 + c0);
#pragma unroll
    for (int nt = 0; nt < 2; ++nt) {
      const int n = wave * 32 + nt * 16 + p;
      const unsigned short* xi = &xs[n][128 + c0];  // xin = tap kk=2 -> k' = 128 + c
      float4 o;
      o.x = (acc[mt][nt][0] + pb.x + bf2f(xi[0])) * sigm(acc[mt + 4][nt][0] + qb.x);
      o.y = (acc[mt][nt][1] + pb.y + bf2f(xi[1])) * sigm(acc[mt + 4][nt][1] + qb.y);
      o.z = (acc[mt][nt][2] + pb.z + bf2f(xi[2])) * sigm(acc[mt + 4][nt][2] + qb.z);
      o.w = (acc[mt][nt][3] + pb.w + bf2f(xi[3])) * sigm(acc[mt + 4][nt][3] + qb.w);
      *(float4*)(pf + (pixbase + n) * 64 + c0) = o;
    }
  }
}

// ---------------- MFMA GLU conv2 on prop: flat in (relu on read) -> fused LN -> NCHW ----------
__global__ __launch_bounds__(256) void k_conv2_mfma(const float* __restrict__ pf,
                                                    const unsigned short* __restrict__ Wb,
                                                    const float* __restrict__ bias,
                                                    const float* __restrict__ lg,
                                                    const float* __restrict__ lb,
                                                    float* __restrict__ out) {
  __shared__ unsigned short xs[128][200];
  const int lane = threadIdx.x & 63, wave = threadIdx.x >> 6;
  const int quad = lane >> 4, p = lane & 15;
  const int n0 = blockIdx.x * 128, t = blockIdx.y, b = blockIdx.z;
  const int i4 = threadIdx.x & 15, pxb = threadIdx.x >> 4;
  for (int kk = 0; kk < 3; ++kk) {
    const float* srcbase =
        pf + ((size_t)(t + kk) * NP + (size_t)b * NPROP + n0) * 64 + i4 * 4;
#pragma unroll
    for (int h = 0; h < 8; ++h) {
      const int px = h * 16 + pxb;
      const float4 v = *(const float4*)(srcbase + (size_t)px * 64);
      const unsigned a0 =
          (unsigned)f2bf(fmaxf(v.x, 0.f)) | ((unsigned)f2bf(fmaxf(v.y, 0.f)) << 16);
      const unsigned a1 =
          (unsigned)f2bf(fmaxf(v.z, 0.f)) | ((unsigned)f2bf(fmaxf(v.w, 0.f)) << 16);
      *(uint2*)&xs[px][kk * 64 + i4 * 4] = make_uint2(a0, a1);
    }
  }
  __syncthreads();
  floatx4 acc[8][2];
#pragma unroll
  for (int mt = 0; mt < 8; ++mt)
#pragma unroll
    for (int nt = 0; nt < 2; ++nt) acc[mt][nt] = (floatx4){0.f, 0.f, 0.f, 0.f};
#pragma unroll
  for (int k0 = 0; k0 < 192; k0 += 32) {
    const bf16x8 b0 = *(const bf16x8*)&xs[wave * 32 + p][k0 + quad * 8];
    const bf16x8 b1 = *(const bf16x8*)&xs[wave * 32 + 16 + p][k0 + quad * 8];
#pragma unroll
    for (int mt = 0; mt < 8; ++mt) {
      const bf16x8 a = *(const bf16x8*)(Wb + (size_t)(mt * 16 + p) * 192 + k0 + quad * 8);
      acc[mt][0] = mfma16(a, b0, acc[mt][0]);
      acc[mt][1] = mfma16(a, b1, acc[mt][1]);
    }
  }
  float o[4][2][4];
  float s1[2] = {0.f, 0.f}, s2[2] = {0.f, 0.f};
#pragma unroll
  for (int mt = 0; mt < 4; ++mt) {
    const int c0 = mt * 16 + quad * 4;
    const float4 pb = *(const float4*)(bias + c0);
    const float4 qb = *(const float4*)(bias + 64 + c0);
#pragma unroll
    for (int nt = 0; nt < 2; ++nt) {
      const int n = wave * 32 + nt * 16 + p;
      const unsigned short* xi = &xs[n][128 + c0];
      const float pbv[4] = {pb.x, pb.y, pb.z, pb.w};
      const float qbv[4] = {qb.x, qb.y, qb.z, qb.w};
#pragma unroll
      for (int r = 0; r < 4; ++r) {
        const float ov =
            (acc[mt][nt][r] + pbv[r] + bf2f(xi[r])) * sigm(acc[mt + 4][nt][r] + qbv[r]);
        o[mt][nt][r] = ov;
        s1[nt] += ov;
        s2[nt] += ov * ov;
      }
    }
  }
#pragma unroll
  for (int nt = 0; nt < 2; ++nt) {
    s1[nt] += __shfl_xor(s1[nt], 16);
    s1[nt] += __shfl_xor(s1[nt], 32);
    s2[nt] += __shfl_xor(s2[nt], 16);
    s2[nt] += __shfl_xor(s2[nt], 32);
  }
  float mean[2], rs[2];
#pragma unroll
  for (int nt = 0; nt < 2; ++nt) {
    mean[nt] = s1[nt] * (1.f / 64.f);
    const float var = s2[nt] * (1.f / 64.f) - mean[nt] * mean[nt];
    rs[nt] = rsqrtf(var + 1e-5f);
  }
#pragma unroll
  for (int mt = 0; mt < 4; ++mt) {
    const int c0 = mt * 16 + quad * 4;
    const float4 lgv = *(const float4*)(lg + c0);
    const float4 lbv = *(const float4*)(lb + c0);
    const float lgr[4] = {lgv.x, lgv.y, lgv.z, lgv.w};
    const float lbr[4] = {lbv.x, lbv.y, lbv.z, lbv.w};
#pragma unroll
    for (int nt = 0; nt < 2; ++nt) {
      const int n = wave * 32 + nt * 16 + p;
#pragma unroll
      for (int r = 0; r < 4; ++r) {
        const int c = c0 + r;
        out[(((size_t)b * 64 + c) * T2 + t) * NPROP + n0 + n] =
            (o[mt][nt][r] - mean[nt]) * rs[nt] * lgr[r] + lbr[r];
      }
    }
  }
}

// ---------------- GLU conv, N==1 tensors ----------------
__global__ __launch_bounds__(64) void k_glu_conv_small1(const float* __restrict__ x,
                                                        const float* __restrict__ W,
                                                        const float* __restrict__ bias,
                                                        float* __restrict__ xfout) {
  __shared__ float xl[192];
  const int c = threadIdx.x;
  const int t = blockIdx.x, b = blockIdx.y;
  for (int r = c; r < 192; r += 64) {
    const int i = r / 3, k = r - (r / 3) * 3;
    xl[r] = x[((size_t)b * 64 + i) * T_IN + (t + k)];
  }
  __syncthreads();
  float p = 0.f, q = 0.f;
  for (int r0 = 0; r0 < 192; r0 += 4) {
    const float4 xv = *(const float4*)(xl + r0);
    const float4 wp = *(const float4*)(W + (size_t)c * 192 + r0);
    const float4 wq = *(const float4*)(W + (size_t)(c + 64) * 192 + r0);
    p += wp.x * xv.x + wp.y * xv.y + wp.z * xv.z + wp.w * xv.w;
    q += wq.x * xv.x + wq.y * xv.y + wq.z * xv.z + wq.w * xv.w;
  }
  const float xin = xl[c * 3 + 2];
  xfout[((size_t)t * 16 + b) * 64 + c] = (p + bias[c] + xin) * sigm(q + bias[c + 64]);
}

__global__ __launch_bounds__(64) void k_glu_conv_small2(const float* __restrict__ xfin,
                                                        const float* __restrict__ W,
                                                        const float* __restrict__ bias,
                                                        const float* __restrict__ lg,
                                                        const float* __restrict__ lb,
                                                        float* __restrict__ out) {
  __shared__ float xl[192];
  const int c = threadIdx.x;
  const int t = blockIdx.x, b = blockIdx.y;
  for (int r = c; r < 192; r += 64) {
    const int i = r / 3, k = r - (r / 3) * 3;
    xl[r] = fmaxf(xfin[((size_t)(t + k) * 16 + b) * 64 + i], 0.f);
  }
  __syncthreads();
  float p = 0.f, q = 0.f;
  for (int r0 = 0; r0 < 192; r0 += 4) {
    const float4 xv = *(const float4*)(xl + r0);
    const float4 wp = *(const float4*)(W + (size_t)c * 192 + r0);
    const float4 wq = *(const float4*)(W + (size_t)(c + 64) * 192 + r0);
    p += wp.x * xv.x + wp.y * xv.y + wp.z * xv.z + wp.w * xv.w;
    q += wq.x * xv.x + wq.y * xv.y + wq.z * xv.z + wq.w * xv.w;
  }
  const float xin = xl[c * 3 + 2];
  const float o = (p + bias[c] + xin) * sigm(q + bias[c + 64]);
  float s1 = o, s2 = o * o;
#pragma unroll
  for (int off = 32; off > 0; off >>= 1) {
    s1 += __shfl_xor(s1, off);
    s2 += __shfl_xor(s2, off);
  }
  const float m = s1 * (1.f / 64.f);
  const float var = s2 * (1.f / 64.f) - m * m;
  out[((size_t)b * 64 + c) * T2 + t] = (o - m) * rsqrtf(var + 1e-5f) * lg[c] + lb[c];
}

// ---------------- MFMA: h0,h1 = rf @ gcn_W[0,1] (split-bf16, ~fp32 accurate) ----------------
__global__ __launch_bounds__(256) void k_gcn_h2(const float* __restrict__ rf,
                                                const unsigned short* __restrict__ wg,
                                                float* __restrict__ h0, float* __restrict__ h1) {
  __shared__ unsigned short xh[64][72], xl[64][72];
  const int tid = threadIdx.x;
  const int i0 = blockIdx.x * 64, t = blockIdx.y;
  {
    const int r = tid >> 2, cg = tid & 3;
    const float* src = rf + ((size_t)t * NR + i0 + r) * 64 + cg * 16;
#pragma unroll
    for (int j = 0; j < 4; ++j) {
      const float4 v = *(const float4*)(src + j * 4);
      split_store4(v, &xh[r][cg * 16 + j * 4], &xl[r][cg * 16 + j * 4]);
    }
  }
  __syncthreads();
  const int lane = tid & 63, wave = tid >> 6, quad = lane >> 4, p = lane & 15;
  floatx4 acc[2][4];
#pragma unroll
  for (int g = 0; g < 2; ++g)
#pragma unroll
    for (int mt = 0; mt < 4; ++mt) acc[g][mt] = (floatx4){0.f, 0.f, 0.f, 0.f};
#pragma unroll
  for (int k0 = 0; k0 < 64; k0 += 32) {
    const bf16x8 bh = *(const bf16x8*)&xh[wave * 16 + p][k0 + quad * 8];
    const bf16x8 bl = *(const bf16x8*)&xl[wave * 16 + p][k0 + quad * 8];
#pragma unroll
    for (int g = 0; g < 2; ++g)
#pragma unroll
      for (int mt = 0; mt < 4; ++mt) {
        const bf16x8 ah = *(const bf16x8*)(wg + g * 8192 + (size_t)(mt * 16 + p) * 64 + k0 + quad * 8);
        const bf16x8 al =
            *(const bf16x8*)(wg + g * 8192 + 4096 + (size_t)(mt * 16 + p) * 64 + k0 + quad * 8);
        acc[g][mt] = mfma16(ah, bh, acc[g][mt]);
        acc[g][mt] = mfma16(ah, bl, acc[g][mt]);
        acc[g][mt] = mfma16(al, bh, acc[g][mt]);
      }
  }
  const size_t row = (size_t)t * NR + i0 + wave * 16 + p;
#pragma unroll
  for (int mt = 0; mt < 4; ++mt) {
    *(floatx4*)(h0 + row * 64 + mt * 16 + quad * 4) = acc[0][mt];
    *(floatx4*)(h1 + row * 64 + mt * 16 + quad * 4) = acc[1][mt];
  }
}

// ---------------- MFMA room final: CSR gathers + GEMM + relu + LN + NCHW ----------------
__global__ __launch_bounds__(256) void k_room_f2(
    const float* __restrict__ rf, const float* __restrict__ h0, const float* __restrict__ h1,
    const float* __restrict__ df, const int* __restrict__ hhrp, const int* __restrict__ hhcol,
    const float* __restrict__ hhwn, const int* __restrict__ hvrp, const int* __restrict__ hvcol,
    const float* __restrict__ hvwn, const int* __restrict__ drrp, const int* __restrict__ drcol,
    const float* __restrict__ MOR, const float* __restrict__ MTR,
    const float* __restrict__ dinv0, const float* __restrict__ dinv1,
    const float* __restrict__ rcdr, const float* __restrict__ rcor,
    const float* __restrict__ rctr, const float* __restrict__ OFW,
    const float* __restrict__ TRW, const unsigned short* __restrict__ wfr,
    const float* __restrict__ bsr, const float* __restrict__ lg, const float* __restrict__ lb,
    float* __restrict__ out) {
  __shared__ unsigned short xh[64][136], xl[64][136];
  __shared__ float gsum[64][68];
  __shared__ float msA[64][17], msB[64][17];
  __shared__ float ofw_s[16][64], trw_s[16][64];
  const int tid = threadIdx.x;
  const int i0 = blockIdx.x * 64, t = blockIdx.y;
  {
    const int r = tid >> 2, cg = tid & 3;
    const int i = i0 + r;
    const size_t rowbase = ((size_t)t * NR + i) * 64 + cg * 16;
    // gcn: self-loop terms + CSR-gathered edge sums (into gsum)
    const float d0 = dinv0[i], d1 = dinv1[i];
    const float d0sq = d0 * d0, d1sq = d1 * d1;
    float4 g[4];
    {
      const float4* p0 = (const float4*)(h0 + rowbase);
      const float4* p1 = (const float4*)(h1 + rowbase);
#pragma unroll
      for (int j = 0; j < 4; ++j) {
        const float4 a = p0[j], b = p1[j];
        g[j].x = a.x * d0sq + b.x * d1sq;
        g[j].y = a.y * d0sq + b.y * d1sq;
        g[j].z = a.z * d0sq + b.z * d1sq;
        g[j].w = a.w * d0sq + b.w * d1sq;
      }
    }
    for (int e = hhrp[i]; e < hhrp[i + 1]; ++e) {
      const int s = hhcol[e];
      const float wn = hhwn[e];
      const float4* ps = (const float4*)(h0 + ((size_t)t * NR + s) * 64 + cg * 16);
#pragma unroll
      for (int j = 0; j < 4; ++j) {
        const float4 v = ps[j];
        g[j].x += wn * v.x; g[j].y += wn * v.y; g[j].z += wn * v.z; g[j].w += wn * v.w;
      }
    }
    for (int e = hvrp[i]; e < hvrp[i + 1]; ++e) {
      const int s = hvcol[e];
      const float wn = hvwn[e];
      const float4* ps = (const float4*)(h1 + ((size_t)t * NR + s) * 64 + cg * 16);
#pragma unroll
      for (int j = 0; j < 4; ++j) {
        const float4 v = ps[j];
        g[j].x += wn * v.x; g[j].y += wn * v.y; g[j].z += wn * v.z; g[j].w += wn * v.w;
      }
    }
#pragma unroll
    for (int j = 0; j < 4; ++j) *(float4*)&gsum[r][cg * 16 + j * 4] = g[j];
    // dr mean gather -> A first 64 K-cols
    float4 a[4];
#pragma unroll
    for (int j = 0; j < 4; ++j) a[j] = make_float4(0.f, 0.f, 0.f, 0.f);
    for (int e = drrp[i]; e < drrp[i + 1]; ++e) {
      const int s = drcol[e];
      const float4* ps = (const float4*)(df + ((size_t)t * ND + s) * 64 + cg * 16);
#pragma unroll
      for (int j = 0; j < 4; ++j) {
        const float4 v = ps[j];
        a[j].x += v.x; a[j].y += v.y; a[j].z += v.z; a[j].w += v.w;
      }
    }
    const float rc = rcdr[i];
#pragma unroll
    for (int j = 0; j < 4; ++j) {
      a[j].x *= rc; a[j].y *= rc; a[j].z *= rc; a[j].w *= rc;
      split_store4(a[j], &xh[r][cg * 16 + j * 4], &xl[r][cg * 16 + j * 4]);
    }
    // rf self -> A second 64 K-cols
    const float4* pr = (const float4*)(rf + rowbase);
#pragma unroll
    for (int j = 0; j < 4; ++j)
      split_store4(pr[j], &xh[r][64 + cg * 16 + j * 4], &xl[r][64 + cg * 16 + j * 4]);
    // tiny-node weighted sums
    const int jm = (tid & 3) * 4;
    const float rco = rcor[i], rct = rctr[i];
    const float4 ma = *(const float4*)(MOR + (size_t)i * 16 + jm);
    const float4 mb = *(const float4*)(MTR + (size_t)i * 16 + jm);
    msA[r][jm] = ma.x * rco; msA[r][jm + 1] = ma.y * rco;
    msA[r][jm + 2] = ma.z * rco; msA[r][jm + 3] = ma.w * rco;
    msB[r][jm] = mb.x * rct; msB[r][jm + 1] = mb.y * rct;
    msB[r][jm + 2] = mb.z * rct; msB[r][jm + 3] = mb.w * rct;
  }
  ((float4*)ofw_s)[tid] = ((const float4*)(OFW + (size_t)t * 1024))[tid];
  ((float4*)trw_s)[tid] = ((const float4*)(TRW + (size_t)t * 1024))[tid];
  __syncthreads();
  const int lane = tid & 63, wave = tid >> 6, quad = lane >> 4, p = lane & 15;
  floatx4 acc[4];
#pragma unroll
  for (int mt = 0; mt < 4; ++mt) acc[mt] = (floatx4){0.f, 0.f, 0.f, 0.f};
#pragma unroll
  for (int k0 = 0; k0 < 128; k0 += 32) {
    const bf16x8 bh = *(const bf16x8*)&xh[wave * 16 + p][k0 + quad * 8];
    const bf16x8 bl = *(const bf16x8*)&xl[wave * 16 + p][k0 + quad * 8];
#pragma unroll
    for (int mt = 0; mt < 4; ++mt) {
      const bf16x8 ah = *(const bf16x8*)(wfr + (size_t)(mt * 16 + p) * 128 + k0 + quad * 8);
      const bf16x8 al = *(const bf16x8*)(wfr + 8192 + (size_t)(mt * 16 + p) * 128 + k0 + quad * 8);
      acc[mt] = mfma16(ah, bh, acc[mt]);
      acc[mt] = mfma16(ah, bl, acc[mt]);
      acc[mt] = mfma16(al, bh, acc[mt]);
    }
  }
  const int rloc = wave * 16 + p;
  const int i = i0 + rloc;
  float o[4][4];
#pragma unroll
  for (int mt = 0; mt < 4; ++mt) {
    const int c0 = mt * 16 + quad * 4;
    const float4 gv = *(const float4*)&gsum[rloc][c0];
    const float4 bb = *(const float4*)(bsr + c0);
    o[mt][0] = acc[mt][0] + gv.x + bb.x;
    o[mt][1] = acc[mt][1] + gv.y + bb.y;
    o[mt][2] = acc[mt][2] + gv.z + bb.z;
    o[mt][3] = acc[mt][3] + gv.w + bb.w;
  }
#pragma unroll
  for (int s = 0; s < 16; ++s) {
    const float wa = msA[rloc][s], wb = msB[rloc][s];
#pragma unroll
    for (int mt = 0; mt < 4; ++mt) {
      const int c0 = mt * 16 + quad * 4;
      const float4 fa = *(const float4*)&ofw_s[s][c0];
      const float4 fb = *(const float4*)&trw_s[s][c0];
      o[mt][0] += wa * fa.x + wb * fb.x;
      o[mt][1] += wa * fa.y + wb * fb.y;
      o[mt][2] += wa * fa.z + wb * fb.z;
      o[mt][3] += wa * fa.w + wb * fb.w;
    }
  }
  float s1 = 0.f, s2 = 0.f;
#pragma unroll
  for (int mt = 0; mt < 4; ++mt)
#pragma unroll
    for (int r = 0; r < 4; ++r) {
      const float v = fmaxf(o[mt][r], 0.f);
      o[mt][r] = v;
      s1 += v;
      s2 += v * v;
    }
  s1 += __shfl_xor(s1, 16); s1 += __shfl_xor(s1, 32);
  s2 += __shfl_xor(s2, 16); s2 += __shfl_xor(s2, 32);
  const float m = s1 * (1.f / 64.f);
  const float var = s2 * (1.f / 64.f) - m * m;
  const float rs = rsqrtf(var + 1e-5f);
  const int b = i >> 8, n = i & 255;
#pragma unroll
  for (int mt = 0; mt < 4; ++mt) {
    const int c0 = mt * 16 + quad * 4;
    const float4 lgv = *(const float4*)(lg + c0);
    const float4 lbv = *(const float4*)(lb + c0);
    out[(((size_t)b * 64 + c0 + 0) * T2 + t) * NROOM + n] = (o[mt][0] - m) * rs * lgv.x + lbv.x;
    out[(((size_t)b * 64 + c0 + 1) * T2 + t) * NROOM + n] = (o[mt][1] - m) * rs * lgv.y + lbv.y;
    out[(((size_t)b * 64 + c0 + 2) * T2 + t) * NROOM + n] = (o[mt][2] - m) * rs * lgv.z + lbv.z;
    out[(((size_t)b * 64 + c0 + 3) * T2 + t) * NROOM + n] = (o[mt][3] - m) * rs * lgv.w + lbv.w;
  }
}

// ---------------- MFMA dev final: CSR gather + GEMM + relu + LN + NCHW ----------------
__global__ __launch_bounds__(256) void k_dev_f2(
    const float* __restrict__ pf, const float* __restrict__ df, const int* __restrict__ pdrp,
    const int* __restrict__ pdcol, const float* __restrict__ rcpd,
    const float* __restrict__ MTD, const float* __restrict__ rctd,
    const float* __restrict__ TDW, const unsigned short* __restrict__ wfd,
    const float* __restrict__ bsd, const float* __restrict__ lg, const float* __restrict__ lb,
    float* __restrict__ out) {
  __shared__ unsigned short xh[64][136], xl[64][136];
  __shared__ float ms[64][17];
  __shared__ float tdw_s[16][64];
  const int tid = threadIdx.x;
  const int i0 = blockIdx.x * 64, t = blockIdx.y;
  {
    const int r = tid >> 2, cg = tid & 3;
    const int i = i0 + r;
    // pd mean gather from pf
    float4 a[4];
#pragma unroll
    for (int j = 0; j < 4; ++j) a[j] = make_float4(0.f, 0.f, 0.f, 0.f);
    for (int e = pdrp[i]; e < pdrp[i + 1]; ++e) {
      const int s = pdcol[e];
      const float4* ps = (const float4*)(pf + ((size_t)t * NP + s) * 64 + cg * 16);
#pragma unroll
      for (int j = 0; j < 4; ++j) {
        const float4 v = ps[j];
        a[j].x += v.x; a[j].y += v.y; a[j].z += v.z; a[j].w += v.w;
      }
    }
    const float rc = rcpd[i];
#pragma unroll
    for (int j = 0; j < 4; ++j) {
      a[j].x *= rc; a[j].y *= rc; a[j].z *= rc; a[j].w *= rc;
      split_store4(a[j], &xh[r][cg * 16 + j * 4], &xl[r][cg * 16 + j * 4]);
    }
    const float4* pd = (const float4*)(df + ((size_t)t * ND + i) * 64 + cg * 16);
#pragma unroll
    for (int j = 0; j < 4; ++j)
      split_store4(pd[j], &xh[r][64 + cg * 16 + j * 4], &xl[r][64 + cg * 16 + j * 4]);
    const int jm = (tid & 3) * 4;
    const float rct = rctd[i];
    const float4 mv = *(const float4*)(MTD + (size_t)i * 16 + jm);
    ms[r][jm] = mv.x * rct; ms[r][jm + 1] = mv.y * rct;
    ms[r][jm + 2] = mv.z * rct; ms[r][jm + 3] = mv.w * rct;
  }
  ((float4*)tdw_s)[tid] = ((const float4*)(TDW + (size_t)t * 1024))[tid];
  __syncthreads();
  const int lane = tid & 63, wave = tid >> 6, quad = lane >> 4, p = lane & 15;
  floatx4 acc[4];
#pragma unroll
  for (int mt = 0; mt < 4; ++mt) acc[mt] = (floatx4){0.f, 0.f, 0.f, 0.f};
#pragma unroll
  for (int k0 = 0; k0 < 128; k0 += 32) {
    const bf16x8 bh = *(const bf16x8*)&xh[wave * 16 + p][k0 + quad * 8];
    const bf16x8 bl = *(const bf16x8*)&xl[wave * 16 + p][k0 + quad * 8];
#pragma unroll
    for (int mt = 0; mt < 4; ++mt) {
      const bf16x8 ah = *(const bf16x8*)(wfd + (size_t)(mt * 16 + p) * 128 + k0 + quad * 8);
      const bf16x8 al = *(const bf16x8*)(wfd + 8192 + (size_t)(mt * 16 + p) * 128 + k0 + quad * 8);
      acc[mt] = mfma16(ah, bh, acc[mt]);
      acc[mt] = mfma16(ah, bl, acc[mt]);
      acc[mt] = mfma16(al, bh, acc[mt]);
    }
  }
  const int rloc = wave * 16 + p;
  const int i = i0 + rloc;
  float o[4][4];
#pragma unroll
  for (int mt = 0; mt < 4; ++mt) {
    const int c0 = mt * 16 + quad * 4;
    const float4 bb = *(const float4*)(bsd + c0);
    o[mt][0] = acc[mt][0] + bb.x;
    o[mt][1] = acc[mt][1] + bb.y;
    o[mt][2] = acc[mt][2] + bb.z;
    o[mt][3] = acc[mt][3] + bb.w;
  }
#pragma unroll
  for (int s = 0; s < 16; ++s) {
    const float w = ms[rloc][s];
#pragma unroll
    for (int mt = 0; mt < 4; ++mt) {
      const int c0 = mt * 16 + quad * 4;
      const float4 f = *(const float4*)&tdw_s[s][c0];
      o[mt][0] += w * f.x; o[mt][1] += w * f.y; o[mt][2] += w * f.z; o[mt][3] += w * f.w;
    }
  }
  float s1 = 0.f, s2 = 0.f;
#pragma unroll
  for (int mt = 0; mt < 4; ++mt)
#pragma unroll
    for (int r = 0; r < 4; ++r) {
      const float v = fmaxf(o[mt][r], 0.f);
      o[mt][r] = v;
      s1 += v;
      s2 += v * v;
    }
  s1 += __shfl_xor(s1, 16); s1 += __shfl_xor(s1, 32);
  s2 += __shfl_xor(s2, 16); s2 += __shfl_xor(s2, 32);
  const float m = s1 * (1.f / 64.f);
  const float var = s2 * (1.f / 64.f) - m * m;
  const float rs = rsqrtf(var + 1e-5f);
  const int b = i >> 10, n = i & 1023;
#pragma unroll
  for (int mt = 0; mt < 4; ++mt) {
    const int c0 = mt * 16 + quad * 4;
    const float4 lgv = *(const float4*)(lg + c0);
    const float4 lbv = *(const float4*)(lb + c0);
    out[(((size_t)b * 64 + c0 + 0) * T2 + t) * NDEV + n] = (o[mt][0] - m) * rs * lgv.x + lbv.x;
    out[(((size_t)b * 64 + c0 + 1) * T2 + t) * NDEV + n] = (o[mt][1] - m) * rs * lgv.y + lbv.y;
    out[(((size_t)b * 64 + c0 + 2) * T2 + t) * NDEV + n] = (o[mt][2] - m) * rs * lgv.z + lbv.z;
    out[(((size_t)b * 64 + c0 + 3) * T2 + t) * NDEV + n] = (o[mt][3] - m) * rs * lgv.w + lbv.w;
  }
}

// ---------------- MFMA prop final: pf = pf@Wr5 + gather@Wl5 + bl5 (in-place) ----------------
__global__ __launch_bounds__(256) void k_prop_f2(float* __restrict__ pf,
                                                 const float* __restrict__ MTP,
                                                 const float* __restrict__ rctp,
                                                 const float* __restrict__ TPW,
                                                 const unsigned short* __restrict__ wfp,
                                                 const float* __restrict__ bl5) {
  __shared__ unsigned short xh[64][72], xl[64][72];
  __shared__ float ms[64][17];
  __shared__ float tpw_s[16][64];
  const int tid = threadIdx.x;
  const int i0 = blockIdx.x * 64, t = blockIdx.y;
  {
    const int r = tid >> 2, cg = tid & 3;
    const float* src = pf + ((size_t)t * NP + i0 + r) * 64 + cg * 16;
#pragma unroll
    for (int j = 0; j < 4; ++j) {
      const float4 v = *(const float4*)(src + j * 4);
      split_store4(v, &xh[r][cg * 16 + j * 4], &xl[r][cg * 16 + j * 4]);
    }
    const int jm = (tid & 3) * 4;
    const float rct = rctp[i0 + r];
    const float4 mv = *(const float4*)(MTP + (size_t)(i0 + r) * 16 + jm);
    ms[r][jm] = mv.x * rct; ms[r][jm + 1] = mv.y * rct;
    ms[r][jm + 2] = mv.z * rct; ms[r][jm + 3] = mv.w * rct;
  }
  ((float4*)tpw_s)[tid] = ((const float4*)(TPW + (size_t)t * 1024))[tid];
  __syncthreads();
  const int lane = tid & 63, wave = tid >> 6, quad = lane >> 4, p = lane & 15;
  floatx4 acc[4];
#pragma unroll
  for (int mt = 0; mt < 4; ++mt) acc[mt] = (floatx4){0.f, 0.f, 0.f, 0.f};
#pragma unroll
  for (int k0 = 0; k0 < 64; k0 += 32) {
    const bf16x8 bh = *(const bf16x8*)&xh[wave * 16 + p][k0 + quad * 8];
    const bf16x8 bl = *(const bf16x8*)&xl[wave * 16 + p][k0 + quad * 8];
#pragma unroll
    for (int mt = 0; mt < 4; ++mt) {
      const bf16x8 ah = *(const bf16x8*)(wfp + (size_t)(mt * 16 + p) * 64 + k0 + quad * 8);
      const bf16x8 al = *(const bf16x8*)(wfp + 4096 + (size_t)(mt * 16 + p) * 64 + k0 + quad * 8);
      acc[mt] = mfma16(ah, bh, acc[mt]);
      acc[mt] = mfma16(ah, bl, acc[mt]);
      acc[mt] = mfma16(al, bh, acc[mt]);
    }
  }
  const int rloc = wave * 16 + p;
  float o[4][4];
#pragma unroll
  for (int mt = 0; mt < 4; ++mt) {
    const int c0 = mt * 16 + quad * 4;
    const float4 bb = *(const float4*)(bl5 + c0);
    o[mt][0] = acc[mt][0] + bb.x;
    o[mt][1] = acc[mt][1] + bb.y;
    o[mt][2] = acc[mt][2] + bb.z;
    o[mt][3] = acc[mt][3] + bb.w;
  }
#pragma unroll
  for (int s = 0; s < 16; ++s) {
    const float w = ms[rloc][s];
#pragma unroll
    for (int mt = 0; mt < 4; ++mt) {
      const int c0 = mt * 16 + quad * 4;
      const float4 f = *(const float4*)&tpw_s[s][c0];
      o[mt][0] += w * f.x; o[mt][1] += w * f.y; o[mt][2] += w * f.z; o[mt][3] += w * f.w;
    }
  }
  const size_t row = (size_t)t * NP + i0 + rloc;
#pragma unroll
  for (int mt = 0; mt < 4; ++mt) {
    const int c0 = mt * 16 + quad * 4;
    float4 st;
    st.x = o[mt][0]; st.y = o[mt][1]; st.z = o[mt][2]; st.w = o[mt][3];
    *(float4*)(pf + row * 64 + c0) = st;
  }
}

// ---------------- host launcher ----------------
extern "C" void kernel_launch(void* const* d_in, const int* in_sizes, int n_in, void* d_out,
                              int out_size, void* d_ws, size_t ws_size, hipStream_t stream) {
  (void)n_in; (void)out_size; (void)ws_size;
  const float* x_room = (const float*)d_in[0];
  const float* x_device = (const float*)d_in[1];
  const float* x_property = (const float*)d_in[2];
  const float* x_outside = (const float*)d_in[3];
  const float* x_time = (const float*)d_in[4];
  const float* conv1_W = (const float*)d_in[5];
  const float* conv1_b = (const float*)d_in[6];
  const float* conv2_W = (const float*)d_in[7];
  const float* conv2_b = (const float*)d_in[8];
  const float* gcn_W = (const float*)d_in[9];
  const float* gcn_b = (const float*)d_in[10];
  const float* sage_Wl = (const float*)d_in[11];
  const float* sage_bl = (const float*)d_in[12];
  const float* sage_Wr = (const float*)d_in[13];
  const float* ln_g = (const float*)d_in[14];
  const float* ln_b = (const float*)d_in[15];
  const float* hh_w = (const float*)d_in[16];
  const float* hv_w = (const float*)d_in[17];
  const int* hh_src = (const int*)d_in[18];
  const int* hh_dst = (const int*)d_in[19];
  const int* hv_src = (const int*)d_in[20];
  const int* hv_dst = (const int*)d_in[21];
  const int* dr_src = (const int*)d_in[22];
  const int* dr_dst = (const int*)d_in[23];
  const int* pd_src = (const int*)d_in[24];
  const int* pd_dst = (const int*)d_in[25];
  const int* or_src = (const int*)d_in[26];
  const int* or_dst = (const int*)d_in[27];
  const int* tr_src = (const int*)d_in[28];
  const int* tr_dst = (const int*)d_in[29];
  const int* td_src = (const int*)d_in[30];
  const int* td_dst = (const int*)d_in[31];
  const int* tp_src = (const int*)d_in[32];
  const int* tp_dst = (const int*)d_in[33];
  const int E_hh = in_sizes[18], E_hv = in_sizes[20], E_dr = in_sizes[22], E_pd = in_sizes[24];
  const int E_or = in_sizes[26], E_tr = in_sizes[28], E_td = in_sizes[30], E_tp = in_sizes[32];

  float* ws = (float*)d_ws;
  float* out = (float*)d_out;
  unsigned short* wb1 = (unsigned short*)(ws + O_WB1);
  unsigned short* wb2 = (unsigned short*)(ws + O_WB2);
  unsigned short* wfd = (unsigned short*)(ws + O_WFD);
  unsigned short* wfr = (unsigned short*)(ws + O_WFR);
  unsigned short* wfp = (unsigned short*)(ws + O_WFP);
  unsigned short* wg  = (unsigned short*)(ws + O_WG);
  int* hhrp = (int*)(ws + O_HHRP); int* hhcur = (int*)(ws + O_HHCUR);
  int* hhcol = (int*)(ws + O_HHCOL); float* hhwn = ws + O_HHWN;
  int* hvrp = (int*)(ws + O_HVRP); int* hvcur = (int*)(ws + O_HVCUR);
  int* hvcol = (int*)(ws + O_HVCOL); float* hvwn = ws + O_HVWN;
  int* drrp = (int*)(ws + O_DRRP); int* drcur = (int*)(ws + O_DRCUR);
  int* drcol = (int*)(ws + O_DRCOL);
  int* pdrp = (int*)(ws + O_PDRP); int* pdcur = (int*)(ws + O_PDCUR);
  int* pdcol = (int*)(ws + O_PDCOL);
  int* cntdr = (int*)(ws + O_CNTDR); int* cntpd = (int*)(ws + O_CNTPD);
  int* chh = (int*)(ws + O_CHH); int* chv = (int*)(ws + O_CHV);

  hipMemsetAsync(ws + O_ZERO, 0, ZERO_CNT * sizeof(float), stream);

  k_prep<<<16, 256, 0, stream>>>(sage_Wr, gcn_b, sage_bl, ws + O_WSR, ws + O_WSD, ws + O_BSR,
                                 ws + O_BSD);
  k_wbf<<<96, 256, 0, stream>>>(conv1_W, conv2_W, wb1, wb2);
  k_wfin<<<112, 256, 0, stream>>>(sage_Wl, sage_Wr, gcn_W, ws + O_WSR, ws + O_WSD, wfd, wfr, wfp,
                                  wg);

  // graph preprocessing: counts -> scalars -> CSR
  k_count_w<<<(E_hh + 255) / 256, 256, 0, stream>>>(hh_dst, hh_w, E_hh, ws + O_DEG0);
  k_count_w<<<(E_hv + 255) / 256, 256, 0, stream>>>(hv_dst, hv_w, E_hv, ws + O_DEG1);
  k_counti<<<(E_hh + 255) / 256, 256, 0, stream>>>(hh_dst, E_hh, chh);
  k_counti<<<(E_hv + 255) / 256, 256, 0, stream>>>(hv_dst, E_hv, chv);
  k_counti<<<(E_dr + 255) / 256, 256, 0, stream>>>(dr_dst, E_dr, cntdr);
  k_counti<<<(E_pd + 255) / 256, 256, 0, stream>>>(pd_dst, E_pd, cntpd);
  k_cmat<<<(E_or + 255) / 256, 256, 0, stream>>>(or_src, or_dst, E_or, ws + O_MOR);
  k_cmat<<<(E_tr + 255) / 256, 256, 0, stream>>>(tr_src, tr_dst, E_tr, ws + O_MTR);
  k_cmat<<<(E_td + 255) / 256, 256, 0, stream>>>(td_src, td_dst, E_td, ws + O_MTD);
  k_cmat<<<(E_tp + 255) / 256, 256, 0, stream>>>(tp_src, tp_dst, E_tp, ws + O_MTP);
  k_finalize<<<256, 256, 0, stream>>>(ws + O_DEG0, ws + O_DEG1, cntdr, cntpd,
                                      ws + O_MOR, ws + O_MTR, ws + O_MTD, ws + O_MTP,
                                      ws + O_DINV0, ws + O_DINV1, ws + O_RCDR, ws + O_RCOR,
                                      ws + O_RCTR, ws + O_RCPD, ws + O_RCTD, ws + O_RCTP);
  k_scan<<<1, 256, 0, stream>>>(chh, 4096, hhrp, hhcur);
  k_scan<<<1, 256, 0, stream>>>(chv, 4096, hvrp, hvcur);
  k_scan<<<1, 256, 0, stream>>>(cntdr, 4096, drrp, drcur);
  k_scan<<<1, 256, 0, stream>>>(cntpd, 16384, pdrp, pdcur);
  k_fill_w<<<(E_hh + 255) / 256, 256, 0, stream>>>(hh_src, hh_dst, hh_w, E_hh, ws + O_DINV0,
                                                   hhcur, hhcol, hhwn);
  k_fill_w<<<(E_hv + 255) / 256, 256, 0, stream>>>(hv_src, hv_dst, hv_w, E_hv, ws + O_DINV1,
                                                   hvcur, hvcol, hvwn);
  k_fill<<<(E_dr + 255) / 256, 256, 0, stream>>>(dr_src, dr_dst, E_dr, drcur, drcol);
  k_fill<<<(E_pd + 255) / 256, 256, 0, stream>>>(pd_src, pd_dst, E_pd, pdcur, pdcol);

  // rf/df only consumed at t < T2
  k_transpose<<<dim3(NROOM / 64, T2, NB), 256, 0, stream>>>(x_room, ws + O_RF, NROOM);
  k_transpose<<<dim3(NDEV / 64, T2, NB), 256, 0, stream>>>(x_device, ws + O_DF, NDEV);

  // GLU conv1 (MFMA for prop, scalar for N==1 tensors) — prop needs all 14 t (conv2 taps)
  k_conv1_mfma<<<dim3(NPROP / 128, T1, NB), 256, 0, stream>>>(x_property, wb1, conv1_b,
                                                              ws + O_PF);
  k_glu_conv_small1<<<dim3(T1, NB), 64, 0, stream>>>(x_outside, conv1_W + 128 * 192,
                                                     conv1_b + 128, ws + O_OF);
  k_glu_conv_small1<<<dim3(T1, NB), 64, 0, stream>>>(x_time, conv1_W + 2 * 128 * 192,
                                                     conv1_b + 2 * 128, ws + O_TF);
  k_wprod<<<224, 256, 0, stream>>>(ws + O_OF, ws + O_TF, sage_Wl, ws + O_OFW);

  k_gcn_h2<<<dim3(NR / 64, T2), 256, 0, stream>>>(ws + O_RF, wg, ws + O_H0, ws + O_H1);

  k_room_f2<<<dim3(NR / 64, T2), 256, 0, stream>>>(
      ws + O_RF, ws + O_H0, ws + O_H1, ws + O_DF, hhrp, hhcol, hhwn, hvrp, hvcol, hvwn, drrp,
      drcol, ws + O_MOR, ws + O_MTR, ws + O_DINV0, ws + O_DINV1, ws + O_RCDR, ws + O_RCOR,
      ws + O_RCTR, ws + O_OFW, ws + O_TRW, wfr, ws + O_BSR, ln_g, ln_b, out + OUT_ROOM);
  k_dev_f2<<<dim3(ND / 64, T2), 256, 0, stream>>>(
      ws + O_PF, ws + O_DF, pdrp, pdcol, ws + O_RCPD, ws + O_MTD, ws + O_RCTD, ws + O_TDW, wfd,
      ws + O_BSD, ln_g + 64, ln_b + 64, out + OUT_DEV);
  k_prop_f2<<<dim3(NP / 64, T1), 256, 0, stream>>>(ws + O_PF, ws + O_MTP, ws + O_RCTP,
                                                   ws + O_TPW, wfp, sage_bl + 5 * 64);

  k_conv2_mfma<<<dim3(NPROP / 128, T2, NB), 256, 0, stream>>>(
      ws + O_PF, wb2, conv2_b, ln_g + 2 * 64, ln_b + 2 * 64, out + OUT_PROP);
  k_glu_conv_small2<<<dim3(T2, NB), 64, 0, stream>>>(ws + O_OF, conv2_W + 128 * 192,
                                                     conv2_b + 128, ln_g + 3 * 64, ln_b + 3 * 64,
                                                     out + OUT_OUT);
  k_glu_conv_small2<<<dim3(T2, NB), 64, 0, stream>>>(ws + O_TF, conv2_W + 2 * 128 * 192,
                                                     conv2_b + 2 * 128, ln_g + 4 * 64,
                                                     ln_b + 4 * 64, out + OUT_TIME);
}